// Round 11
// baseline (442.983 us; speedup 1.0000x reference)
//
#include <hip/hip_runtime.h>
#include <cstdint>
#include <cstddef>

#define N_NODES 2048
#define N_PTS 256
#define N_EDGE 32768
#define N_EDGE_TOT (N_EDGE + N_NODES)  // 34816, with self-loops appended
#define NPG 32                          // nodes per graph (2048/64)

typedef __attribute__((ext_vector_type(8))) short bfx8;
typedef __attribute__((ext_vector_type(4))) float f32x4;
typedef unsigned short ushort_t;

#define MFMA16(a, b, c) __builtin_amdgcn_mfma_f32_16x16x32_bf16(a, b, c, 0, 0, 0)

// ---------- helpers ----------
__device__ inline int e_src(const int* ei, int e) { return e < N_EDGE ? ei[e] : e - N_EDGE; }
__device__ inline int e_dst(const int* ei, int e) { return e < N_EDGE ? ei[N_EDGE + e] : e - N_EDGE; }

// HW packed f32->bf16 (RTNE): dst[15:0]=bf16(a), dst[31:16]=bf16(b).
__device__ inline unsigned cvtpk_bf16(float a, float b) {
  unsigned r;
  asm("v_cvt_pk_bf16_f32 %0, %1, %2" : "=v"(r) : "v"(a), "v"(b));
  return r;
}
// split 2 floats -> packed hi pair + packed lo pair (residuals exact)
__device__ inline void split2pk(float a, float b, unsigned& hp, unsigned& lp) {
  hp = cvtpk_bf16(a, b);
  float ha = __uint_as_float(hp << 16);
  float hb = __uint_as_float(hp & 0xffff0000u);
  lp = cvtpk_bf16(a - ha, b - hb);
}

// ---------- graph build: CSR of in-edges grouped by dst ----------
__global__ void k_hist(const int* __restrict__ ei, int* __restrict__ cnt) {
  int e = blockIdx.x * 256 + threadIdx.x;
  if (e >= N_EDGE_TOT) return;
  atomicAdd(&cnt[e_dst(ei, e)], 1);
}

// scan + re-zero cnt (folds the second memset; replay-safe: pre-hist memset remains)
__global__ __launch_bounds__(256) void k_scan(int* __restrict__ cnt, int* __restrict__ row_ptr) {
  __shared__ int sS[256];
  const int t = threadIdx.x;
  int v[8]; int s = 0;
#pragma unroll
  for (int i = 0; i < 8; i++) { v[i] = cnt[t * 8 + i]; s += v[i]; }
#pragma unroll
  for (int i = 0; i < 8; i++) cnt[t * 8 + i] = 0;  // cnt reused as cursor by k_scatter
  sS[t] = s;
  __syncthreads();
  for (int off = 1; off < 256; off <<= 1) {
    int x = 0;
    if (t >= off) x = sS[t - off];
    __syncthreads();
    sS[t] += x;
    __syncthreads();
  }
  int run = sS[t] - s;  // exclusive prefix
#pragma unroll
  for (int i = 0; i < 8; i++) { row_ptr[t * 8 + i] = run; run += v[i]; }
  if (t == 255) row_ptr[2048] = run;
}

__global__ void k_scatter(const int* __restrict__ ei, const int* __restrict__ row_ptr,
                          int* __restrict__ cur, int* __restrict__ edge_list) {
  int e = blockIdx.x * 256 + threadIdx.x;
  if (e >= N_EDGE_TOT) return;
  int d = e_dst(ei, e);
  int pos = row_ptr[d] + atomicAdd(&cur[d], 1);
  edge_list[pos] = e;
}

// ---------- tiled weight prep: [K][N] -> [N][K], split hi/lo bf16, coalesced ----------
__device__ inline void split_tile(const float* __restrict__ src, ushort_t* __restrict__ dh,
                                  ushort_t* __restrict__ dl, int K, int N,
                                  int k0, int n0, int t) {
  __shared__ float sT[64][65];
  const int lr = t >> 4, lc = (t & 15) * 4;
#pragma unroll
  for (int p = 0; p < 4; p++) {
    int k = lr + p * 16;
    float4 v = *(const float4*)(src + (size_t)(k0 + k) * N + n0 + lc);
    sT[k][lc] = v.x; sT[k][lc + 1] = v.y; sT[k][lc + 2] = v.z; sT[k][lc + 3] = v.w;
  }
  __syncthreads();
  const int wr = t >> 4, wc = (t & 15) * 4;
#pragma unroll
  for (int p = 0; p < 4; p++) {
    int nrow = wr + p * 16;
    uint2 uh, ul;
    split2pk(sT[wc + 0][nrow], sT[wc + 1][nrow], uh.x, ul.x);
    split2pk(sT[wc + 2][nrow], sT[wc + 3][nrow], uh.y, ul.y);
    *(uint2*)(dh + (size_t)(n0 + nrow) * K + k0 + wc) = uh;
    *(uint2*)(dl + (size_t)(n0 + nrow) * K + k0 + wc) = ul;
  }
}

// ushort sub-offsets (units: ushorts, from OFF_USH)
constexpr size_t U_W2H = 0,       U_W2L = 4096;
constexpr size_t U_W3H = 8192,    U_W3L = 12288;
constexpr size_t U_W4H = 16384,   U_W4L = 24576;
constexpr size_t U_W5H = 32768,   U_W5L = 98304;   // end 163840
constexpr size_t U_MFH = 163840,  U_MFL = 688128;  // 1024x512, end 1212416
constexpr size_t U_G1H = 1212416;                   // [1024][512] hi (wl|wr)
constexpr size_t U_G1L = 1736704;                   // [1024][512] lo
constexpr size_t U_G2H = 2260992;
constexpr size_t U_G2L = 2785280;                   // end 3309568
constexpr size_t U_CL1H = 3309568, U_CL1L = 3342336;  // end 3375104
constexpr size_t U_END  = 3375104;

// ALL weight splits in one launch (412 blocks):
// z 0..19: pointnet (w2,w3,w4,w5); z 20..147: mf_w2; z 148..403: GAT wl/wr x2;
// z 404..411: cl_w1. Non-PN regions gated by `full`.
__global__ __launch_bounds__(256) void k_split_all(
    const float* __restrict__ w2, const float* __restrict__ w3,
    const float* __restrict__ w4, const float* __restrict__ w5,
    const float* __restrict__ mfw, const float* __restrict__ g1l,
    const float* __restrict__ g1r, const float* __restrict__ g2l,
    const float* __restrict__ g2r, const float* __restrict__ clw,
    ushort_t* __restrict__ ush, int full) {
  const int z = blockIdx.x;
  const int t = threadIdx.x;
  if (z < 20) {
    const float* src; ushort_t* dh; ushort_t* dl; int K, N, k0, n0;
    if (z == 0)      { src = w2; dh = ush + U_W2H; dl = ush + U_W2L; K = 64;  N = 64;  k0 = 0; n0 = 0; }
    else if (z == 1) { src = w3; dh = ush + U_W3H; dl = ush + U_W3L; K = 64;  N = 64;  k0 = 0; n0 = 0; }
    else if (z < 4)  { src = w4; dh = ush + U_W4H; dl = ush + U_W4L; K = 64;  N = 128; k0 = 0; n0 = (z - 2) * 64; }
    else { int i = z - 4; src = w5; dh = ush + U_W5H; dl = ush + U_W5L; K = 128; N = 512;
           k0 = (i >> 3) * 64; n0 = (i & 7) * 64; }
    split_tile(src, dh, dl, K, N, k0, n0, t);
  } else if (!full) {
    return;
  } else if (z < 148) {
    int i = z - 20;  // 16 k-tiles x 8 n-tiles
    split_tile(mfw, ush + U_MFH, ush + U_MFL, 1024, 512, (i >> 3) * 64, (i & 7) * 64, t);
  } else if (z < 404) {
    int i = z - 148;
    int m = i >> 6, tile = i & 63;
    const float* src = (m == 0) ? g1l : (m == 1) ? g1r : (m == 2) ? g2l : g2r;
    ushort_t* dh = ush + U_G1H + (size_t)(m >> 1) * 1048576 + (size_t)(m & 1) * 262144;
    ushort_t* dl = dh + 524288;
    split_tile(src, dh, dl, 512, 512, (tile >> 3) * 64, (tile & 7) * 64, t);
  } else {
    int i = z - 404;  // 8 k-tiles x 1
    split_tile(clw, ush + U_CL1H, ush + U_CL1L, 512, 64, i * 64, 0, t);
  }
}

// ---------- PointNet fused, split-bf16 MFMA (3-pass), LDS-resident ----------
// ROUND-2 STRUCTURE (register-safe: VGPR 96, zero spill) + cvt_pk-based splits.
// FROZEN: restructures spill (rounds 4/6); barrier cuts are neutral (round 8).
// Near structural limit: MFMA pipe ~saturated during MFMA phases (39.5% util
// = 112us ~ 124us issue floor); rest is phase-locked VALU epilogue + barriers
// at 1 block/CU (148 KB LDS).
__global__ __launch_bounds__(512, 2) void k_pointnet(
    const float* __restrict__ pcd, const float* __restrict__ w1,
    const ushort_t* __restrict__ w2th, const ushort_t* __restrict__ w2tl,
    const ushort_t* __restrict__ w3th, const ushort_t* __restrict__ w3tl,
    const ushort_t* __restrict__ w4th, const ushort_t* __restrict__ w4tl,
    const ushort_t* __restrict__ w5th, const ushort_t* __restrict__ w5tl,
    float* __restrict__ xcat) {
  __shared__ ushort_t sH4H[256 * 128];  // 64 KB, swizzled [row][128]
  __shared__ ushort_t sH4L[256 * 128];  // 64 KB
  __shared__ ushort_t sBAH[32 * 64];    // 4 KB ping
  __shared__ ushort_t sBAL[32 * 64];
  __shared__ ushort_t sBBH[32 * 64];    // 4 KB pong
  __shared__ ushort_t sBBL[32 * 64];
  __shared__ float sP[256 * 3];
  __shared__ float sW1[3 * 64];

  char* H4H = (char*)sH4H; char* H4L = (char*)sH4L;
  char* BAH = (char*)sBAH; char* BAL = (char*)sBAL;
  char* BBH = (char*)sBBH; char* BBL = (char*)sBBL;

  const int t = threadIdx.x;
  const int node = blockIdx.x;
  const int w = t >> 6;
  const int lane = t & 63;
  const int l15 = lane & 15;
  const int kg = lane >> 4;  // 0..3

  // stage pcd + w1
  for (int i = t; i < 768; i += 512) sP[i] = pcd[(size_t)node * 768 + i];
  for (int i = t; i < 192; i += 512) sW1[i] = w1[i];

  // cache per-wave B-fragments for L2-L4 in VGPRs (loaded once)
  const int rt14 = w >> 2;  // 0..1
  const int ct14 = w & 3;   // 0..3
  bfx8 b2h[2], b2l[2], b3h[2], b3l[2], b4h[2][2], b4l[2][2];
#pragma unroll
  for (int ks = 0; ks < 2; ks++) {
    {
      int col = ct14 * 16 + l15;
      int k = ks * 32 + kg * 8;
      b2h[ks] = *(const bfx8*)(w2th + col * 64 + k);
      b2l[ks] = *(const bfx8*)(w2tl + col * 64 + k);
      b3h[ks] = *(const bfx8*)(w3th + col * 64 + k);
      b3l[ks] = *(const bfx8*)(w3tl + col * 64 + k);
    }
#pragma unroll
    for (int u = 0; u < 2; u++) {
      int col = (ct14 * 2 + u) * 16 + l15;
      int k = ks * 32 + kg * 8;
      b4h[u][ks] = *(const bfx8*)(w4th + col * 64 + k);
      b4l[u][ks] = *(const bfx8*)(w4tl + col * 64 + k);
    }
  }
  __syncthreads();

  // L1 thread mapping (all 512 threads): 32 rows x 64 cols
  const int l1r = t >> 4, l1c = t & 15;

  // ---------------- phase 1: L1-L4 over 8 chunks of 32 points ----------------
  // prologue: L1(0) -> BA
  {
    const float* p = &sP[(0 * 32 + l1r) * 3];
    float p0 = p[0], p1 = p[1], p2 = p[2];
    float vv[4];
#pragma unroll
    for (int j = 0; j < 4; j++) {
      int col = l1c * 4 + j;
      vv[j] = fmaxf(fmaf(p0, sW1[col], fmaf(p1, sW1[64 + col], p2 * sW1[128 + col])), 0.0f);
    }
    unsigned hp0, lp0, hp1, lp1;
    split2pk(vv[0], vv[1], hp0, lp0);
    split2pk(vv[2], vv[3], hp1, lp1);
    int off = (l1r * 128 + l1c * 8) ^ ((l1r & 7) << 4);
    *(unsigned*)(BAH + off) = hp0;
    *(unsigned*)(BAH + off + 4) = hp1;
    *(unsigned*)(BAL + off) = lp0;
    *(unsigned*)(BAL + off + 4) = lp1;
  }
  __syncthreads();

  for (int c = 0; c < 8; c++) {
    // ping-pong roles: A holds this chunk's L1 output
    char* Ah = (c & 1) ? BBH : BAH;
    char* Al = (c & 1) ? BBL : BAL;
    char* Bh = (c & 1) ? BAH : BBH;
    char* Bl = (c & 1) ? BAL : BBL;
    // L2: A -> B
    {
      f32x4 acc = {0.f, 0.f, 0.f, 0.f};
#pragma unroll
      for (int ks = 0; ks < 2; ks++) {
        int row = rt14 * 16 + l15;
        int k0 = ks * 32 + kg * 8;
        int offb = (row * 128 + k0 * 2) ^ ((row & 7) << 4);
        bfx8 ah = *(const bfx8*)(Ah + offb);
        bfx8 al = *(const bfx8*)(Al + offb);
        acc = MFMA16(ah, b2h[ks], acc);
        acc = MFMA16(al, b2h[ks], acc);
        acc = MFMA16(ah, b2l[ks], acc);
      }
      unsigned hp[2], lp[2];
      split2pk(fmaxf(acc[0], 0.f), fmaxf(acc[1], 0.f), hp[0], lp[0]);
      split2pk(fmaxf(acc[2], 0.f), fmaxf(acc[3], 0.f), hp[1], lp[1]);
      const int colb = (ct14 * 16 + l15) * 2;
      const int rowb = rt14 * 16 + kg * 4;
#pragma unroll
      for (int j = 0; j < 4; j++) {
        int row = rowb + j;
        int off = (row * 128 + colb) ^ ((row & 7) << 4);
        *(ushort_t*)(Bh + off) = (ushort_t)(hp[j >> 1] >> ((j & 1) * 16));
        *(ushort_t*)(Bl + off) = (ushort_t)(lp[j >> 1] >> ((j & 1) * 16));
      }
    }
    __syncthreads();
    // L3: B -> A
    {
      f32x4 acc = {0.f, 0.f, 0.f, 0.f};
#pragma unroll
      for (int ks = 0; ks < 2; ks++) {
        int row = rt14 * 16 + l15;
        int k0 = ks * 32 + kg * 8;
        int offb = (row * 128 + k0 * 2) ^ ((row & 7) << 4);
        bfx8 ah = *(const bfx8*)(Bh + offb);
        bfx8 al = *(const bfx8*)(Bl + offb);
        acc = MFMA16(ah, b3h[ks], acc);
        acc = MFMA16(al, b3h[ks], acc);
        acc = MFMA16(ah, b3l[ks], acc);
      }
      unsigned hp[2], lp[2];
      split2pk(fmaxf(acc[0], 0.f), fmaxf(acc[1], 0.f), hp[0], lp[0]);
      split2pk(fmaxf(acc[2], 0.f), fmaxf(acc[3], 0.f), hp[1], lp[1]);
      const int colb = (ct14 * 16 + l15) * 2;
      const int rowb = rt14 * 16 + kg * 4;
#pragma unroll
      for (int j = 0; j < 4; j++) {
        int row = rowb + j;
        int off = (row * 128 + colb) ^ ((row & 7) << 4);
        *(ushort_t*)(Ah + off) = (ushort_t)(hp[j >> 1] >> ((j & 1) * 16));
        *(ushort_t*)(Al + off) = (ushort_t)(lp[j >> 1] >> ((j & 1) * 16));
      }
    }
    __syncthreads();
    // L4: A -> H4 rows [c*32, c*32+32)  (+ L1(c+1) -> B, overlapped)
    {
      f32x4 acc[2];
      acc[0] = (f32x4){0.f, 0.f, 0.f, 0.f};
      acc[1] = (f32x4){0.f, 0.f, 0.f, 0.f};
#pragma unroll
      for (int ks = 0; ks < 2; ks++) {
        int row = rt14 * 16 + l15;
        int k0 = ks * 32 + kg * 8;
        int offb = (row * 128 + k0 * 2) ^ ((row & 7) << 4);
        bfx8 ah = *(const bfx8*)(Ah + offb);
        bfx8 al = *(const bfx8*)(Al + offb);
#pragma unroll
        for (int u = 0; u < 2; u++) {
          acc[u] = MFMA16(ah, b4h[u][ks], acc[u]);
          acc[u] = MFMA16(al, b4h[u][ks], acc[u]);
          acc[u] = MFMA16(ah, b4l[u][ks], acc[u]);
        }
      }
      // L1 for next chunk, writes B (disjoint from A and H4) — VALU overlaps MFMA
      if (c < 7) {
        const float* p = &sP[((c + 1) * 32 + l1r) * 3];
        float p0 = p[0], p1 = p[1], p2 = p[2];
        float vv[4];
#pragma unroll
        for (int j = 0; j < 4; j++) {
          int col = l1c * 4 + j;
          vv[j] = fmaxf(fmaf(p0, sW1[col], fmaf(p1, sW1[64 + col], p2 * sW1[128 + col])), 0.0f);
        }
        unsigned hp0, lp0, hp1, lp1;
        split2pk(vv[0], vv[1], hp0, lp0);
        split2pk(vv[2], vv[3], hp1, lp1);
        int off = (l1r * 128 + l1c * 8) ^ ((l1r & 7) << 4);
        *(unsigned*)(Bh + off) = hp0;
        *(unsigned*)(Bh + off + 4) = hp1;
        *(unsigned*)(Bl + off) = lp0;
        *(unsigned*)(Bl + off + 4) = lp1;
      }
      // H4 write: pair across u (same row, cols 32B apart)
#pragma unroll
      for (int j = 0; j < 4; j++) {
        unsigned hp, lp;
        split2pk(fmaxf(acc[0][j], 0.f), fmaxf(acc[1][j], 0.f), hp, lp);
        int row = c * 32 + rt14 * 16 + kg * 4 + j;
        int col0 = (ct14 * 2) * 16 + l15;      // u=0 feature
        int off0 = (row * 256 + col0 * 2) ^ ((row & 7) << 4);
        int off1 = ((row * 256 + (col0 + 16) * 2)) ^ ((row & 7) << 4);
        *(ushort_t*)(H4H + off0) = (ushort_t)hp;
        *(ushort_t*)(H4H + off1) = (ushort_t)(hp >> 16);
        *(ushort_t*)(H4L + off0) = (ushort_t)lp;
        *(ushort_t*)(H4L + off1) = (ushort_t)(lp >> 16);
      }
    }
    __syncthreads();
  }

  // ---------------- phase 2: L5 (256x512x128) + relu + maxpool ----------------
  __builtin_amdgcn_sched_barrier(0);  // keep b5 loads out of phase 1 (VGPR pressure)
  bfx8 b5h[4][4], b5l[4][4];  // [ks][ct]
  const int c0 = w * 64;
#pragma unroll
  for (int ks = 0; ks < 4; ks++)
#pragma unroll
    for (int ct = 0; ct < 4; ct++) {
      int col = c0 + ct * 16 + l15;
      int k = ks * 32 + kg * 8;
      b5h[ks][ct] = *(const bfx8*)(w5th + col * 128 + k);
      b5l[ks][ct] = *(const bfx8*)(w5tl + col * 128 + k);
    }
  float runmax[4] = {0.f, 0.f, 0.f, 0.f};  // relu => max >= 0
  for (int rc = 0; rc < 8; rc++) {
    f32x4 acc[2][4];
#pragma unroll
    for (int rt = 0; rt < 2; rt++)
#pragma unroll
      for (int ct = 0; ct < 4; ct++) acc[rt][ct] = (f32x4){0.f, 0.f, 0.f, 0.f};
#pragma unroll
    for (int ks = 0; ks < 4; ks++) {
      bfx8 ah[2], al[2];
#pragma unroll
      for (int rt = 0; rt < 2; rt++) {
        int row = rc * 32 + rt * 16 + l15;
        int k0 = ks * 32 + kg * 8;
        int off = (row * 256 + k0 * 2) ^ ((row & 7) << 4);
        ah[rt] = *(const bfx8*)(H4H + off);
        al[rt] = *(const bfx8*)(H4L + off);
      }
#pragma unroll
      for (int ct = 0; ct < 4; ct++)
#pragma unroll
        for (int rt = 0; rt < 2; rt++) {
          acc[rt][ct] = MFMA16(ah[rt], b5h[ks][ct], acc[rt][ct]);
          acc[rt][ct] = MFMA16(al[rt], b5h[ks][ct], acc[rt][ct]);
          acc[rt][ct] = MFMA16(ah[rt], b5l[ks][ct], acc[rt][ct]);
        }
    }
#pragma unroll
    for (int ct = 0; ct < 4; ct++)
#pragma unroll
      for (int rt = 0; rt < 2; rt++)
#pragma unroll
        for (int j = 0; j < 4; j++)
          runmax[ct] = fmaxf(runmax[ct], acc[rt][ct][j]);
  }
#pragma unroll
  for (int ct = 0; ct < 4; ct++) {
    float m = runmax[ct];
    m = fmaxf(m, __shfl_xor(m, 16));
    m = fmaxf(m, __shfl_xor(m, 32));
    if (lane < 16) xcat[(size_t)node * 1024 + c0 + ct * 16 + lane] = m;
  }
}

// ---------- multi-feature MLP part 1 (fallback path only) ----------
__global__ void k_vdf(const float* __restrict__ vol, const float* __restrict__ dist,
                      const float* __restrict__ ec, const float* __restrict__ w1,
                      const float* __restrict__ b1, float* __restrict__ xcat) {
  int idx = blockIdx.x * 256 + threadIdx.x;  // 2048*512
  int n = idx >> 9, j = idx & 511;
  float v = vol[n] * w1[j] + dist[n] * w1[512 + j] + ec[n] * w1[1024 + j] + b1[j];
  xcat[(size_t)n * 1024 + 512 + j] = fmaxf(v, 0.0f);
}

// ---------- split-bf16 MFMA GEMM, 64x64 tile (mf/classifier) ----------
template <int ACT>
__global__ __launch_bounds__(256) void k_mgemm(const float* __restrict__ A,
                                               const ushort_t* __restrict__ Bh,
                                               const ushort_t* __restrict__ Bl,
                                               const float* __restrict__ bias,
                                               const float* __restrict__ bias2,
                                               float* __restrict__ C,
                                               int M, int N, int K) {
  __shared__ ushort_t sAh[4096], sAl[4096], sBh[4096], sBl[4096];  // 32 KB
  char* pAh = (char*)sAh; char* pAl = (char*)sAl;
  char* pBh = (char*)sBh; char* pBl = (char*)sBl;
  const int t = threadIdx.x;
  const int w = t >> 6, lane = t & 63, l15 = lane & 15, kg = lane >> 4;
  const int row0 = blockIdx.x * 64, col0 = blockIdx.y * 64;
  const int sr = t >> 2;          // stage row (A) / col (B), 0..63
  const int sc = (t & 3) * 16;    // stage k offset
  const int sswz = (sr & 7) << 4;
  const int sbase = sr * 128 + sc * 2;
  f32x4 acc[4];
#pragma unroll
  for (int ct = 0; ct < 4; ct++) acc[ct] = (f32x4){0.f, 0.f, 0.f, 0.f};

  for (int kb = 0; kb < K; kb += 64) {
    __syncthreads();
    {
      const float* Ap = A + (size_t)(row0 + sr) * K + kb + sc;
      float4 a0 = *(const float4*)(Ap);
      float4 a1 = *(const float4*)(Ap + 4);
      float4 a2 = *(const float4*)(Ap + 8);
      float4 a3 = *(const float4*)(Ap + 12);
      union { bfx8 v; unsigned u[4]; } vh0, vh1, vl0, vl1;
      split2pk(a0.x, a0.y, vh0.u[0], vl0.u[0]);
      split2pk(a0.z, a0.w, vh0.u[1], vl0.u[1]);
      split2pk(a1.x, a1.y, vh0.u[2], vl0.u[2]);
      split2pk(a1.z, a1.w, vh0.u[3], vl0.u[3]);
      split2pk(a2.x, a2.y, vh1.u[0], vl1.u[0]);
      split2pk(a2.z, a2.w, vh1.u[1], vl1.u[1]);
      split2pk(a3.x, a3.y, vh1.u[2], vl1.u[2]);
      split2pk(a3.z, a3.w, vh1.u[3], vl1.u[3]);
      *(bfx8*)(pAh + ((sbase) ^ sswz)) = vh0.v;
      *(bfx8*)(pAh + ((sbase + 16) ^ sswz)) = vh1.v;
      *(bfx8*)(pAl + ((sbase) ^ sswz)) = vl0.v;
      *(bfx8*)(pAl + ((sbase + 16) ^ sswz)) = vl1.v;
    }
    {
      const ushort_t* Bph = Bh + (size_t)(col0 + sr) * K + kb + sc;
      const ushort_t* Bpl = Bl + (size_t)(col0 + sr) * K + kb + sc;
      bfx8 b0 = *(const bfx8*)Bph, b1 = *(const bfx8*)(Bph + 8);
      bfx8 c0v = *(const bfx8*)Bpl, c1v = *(const bfx8*)(Bpl + 8);
      *(bfx8*)(pBh + ((sbase) ^ sswz)) = b0;
      *(bfx8*)(pBh + ((sbase + 16) ^ sswz)) = b1;
      *(bfx8*)(pBl + ((sbase) ^ sswz)) = c0v;
      *(bfx8*)(pBl + ((sbase + 16) ^ sswz)) = c1v;
    }
    __syncthreads();
#pragma unroll
    for (int ks = 0; ks < 2; ks++) {
      const int arow = w * 16 + l15;
      const int k2 = (ks * 32 + kg * 8) * 2;
      const int aoff = (arow * 128 + k2) ^ ((arow & 7) << 4);
      bfx8 ah = *(const bfx8*)(pAh + aoff);
      bfx8 al = *(const bfx8*)(pAl + aoff);
#pragma unroll
      for (int ct = 0; ct < 4; ct++) {
        const int bcol = ct * 16 + l15;
        const int boff = (bcol * 128 + k2) ^ ((bcol & 7) << 4);
        bfx8 bh = *(const bfx8*)(pBh + boff);
        bfx8 bl = *(const bfx8*)(pBl + boff);
        acc[ct] = MFMA16(ah, bh, acc[ct]);
        acc[ct] = MFMA16(al, bh, acc[ct]);
        acc[ct] = MFMA16(ah, bl, acc[ct]);
      }
    }
  }
#pragma unroll
  for (int ct = 0; ct < 4; ct++)
#pragma unroll
    for (int j = 0; j < 4; j++) {
      int r = row0 + w * 16 + kg * 4 + j;
      int cc = col0 + ct * 16 + l15;
      float b = (cc < 512) ? bias[cc] : bias2[cc - 512];
      float v = acc[ct][j] + b;
      if (ACT == 1) v = fmaxf(v, 0.0f);
      C[(size_t)r * N + cc] = v;
    }
}

// ---------- split-bf16 MFMA GEMM, 64x128 tile (GAT merged wl|wr transforms) ----------
// 256 threads = 4 waves; wave (rgrp = w>>1, cgrp = w&1) owns 32 rows x 64 cols.
// A restaged N/128 = 8x (vs 16x at 64-wide); B-frags reused across rt (2 MFMA/read).
__global__ __launch_bounds__(256) void k_mgemm2(const float* __restrict__ A,
                                                const ushort_t* __restrict__ Bh,
                                                const ushort_t* __restrict__ Bl,
                                                const float* __restrict__ bias,
                                                const float* __restrict__ bias2,
                                                float* __restrict__ C,
                                                int M, int N, int K) {
  __shared__ ushort_t sAh[4096], sAl[4096];   // 64 rows x 64 k  (16 KB)
  __shared__ ushort_t sBh[8192], sBl[8192];   // 128 cols x 64 k (32 KB)
  char* pAh = (char*)sAh; char* pAl = (char*)sAl;
  char* pBh = (char*)sBh; char* pBl = (char*)sBl;
  const int t = threadIdx.x;
  const int w = t >> 6, lane = t & 63, l15 = lane & 15, kg = lane >> 4;
  const int rgrp = w >> 1, cgrp = w & 1;
  const int row0 = blockIdx.x * 64, col0 = blockIdx.y * 128;
  // A staging map: 64 rows, 16 floats/thread
  const int sr = t >> 2, sc = (t & 3) * 16;
  const int sswz = (sr & 7) << 4;
  const int sbase = sr * 128 + sc * 2;
  // B staging map: 128 cols, 64B (4 chunks)/thread
  const int bcolS = t & 127, bkS = (t >> 7) * 32;
  f32x4 acc[2][4];
#pragma unroll
  for (int rt = 0; rt < 2; rt++)
#pragma unroll
    for (int ct = 0; ct < 4; ct++) acc[rt][ct] = (f32x4){0.f, 0.f, 0.f, 0.f};

  for (int kb = 0; kb < K; kb += 64) {
    __syncthreads();
    {
      const float* Ap = A + (size_t)(row0 + sr) * K + kb + sc;
      float4 a0 = *(const float4*)(Ap);
      float4 a1 = *(const float4*)(Ap + 4);
      float4 a2 = *(const float4*)(Ap + 8);
      float4 a3 = *(const float4*)(Ap + 12);
      union { bfx8 v; unsigned u[4]; } vh0, vh1, vl0, vl1;
      split2pk(a0.x, a0.y, vh0.u[0], vl0.u[0]);
      split2pk(a0.z, a0.w, vh0.u[1], vl0.u[1]);
      split2pk(a1.x, a1.y, vh0.u[2], vl0.u[2]);
      split2pk(a1.z, a1.w, vh0.u[3], vl0.u[3]);
      split2pk(a2.x, a2.y, vh1.u[0], vl1.u[0]);
      split2pk(a2.z, a2.w, vh1.u[1], vl1.u[1]);
      split2pk(a3.x, a3.y, vh1.u[2], vl1.u[2]);
      split2pk(a3.z, a3.w, vh1.u[3], vl1.u[3]);
      *(bfx8*)(pAh + ((sbase) ^ sswz)) = vh0.v;
      *(bfx8*)(pAh + ((sbase + 16) ^ sswz)) = vh1.v;
      *(bfx8*)(pAl + ((sbase) ^ sswz)) = vl0.v;
      *(bfx8*)(pAl + ((sbase + 16) ^ sswz)) = vl1.v;
    }
    {
      const ushort_t* Bph = Bh + (size_t)(col0 + bcolS) * K + kb + bkS;
      const ushort_t* Bpl = Bl + (size_t)(col0 + bcolS) * K + kb + bkS;
      const int bswz = (bcolS & 7) << 4;
      const int bbase = bcolS * 128 + bkS * 2;
#pragma unroll
      for (int q = 0; q < 4; q++) {
        bfx8 bh = *(const bfx8*)(Bph + q * 8);
        bfx8 bl = *(const bfx8*)(Bpl + q * 8);
        *(bfx8*)(pBh + ((bbase + q * 16) ^ bswz)) = bh;
        *(bfx8*)(pBl + ((bbase + q * 16) ^ bswz)) = bl;
      }
    }
    __syncthreads();
#pragma unroll
    for (int ks = 0; ks < 2; ks++) {
      const int k2 = (ks * 32 + kg * 8) * 2;
      bfx8 ah[2], al[2];
#pragma unroll
      for (int rt = 0; rt < 2; rt++) {
        const int arow = rgrp * 32 + rt * 16 + l15;
        const int aoff = (arow * 128 + k2) ^ ((arow & 7) << 4);
        ah[rt] = *(const bfx8*)(pAh + aoff);
        al[rt] = *(const bfx8*)(pAl + aoff);
      }
#pragma unroll
      for (int ct = 0; ct < 4; ct++) {
        const int bcol = cgrp * 64 + ct * 16 + l15;
        const int boff = (bcol * 128 + k2) ^ ((bcol & 7) << 4);
        bfx8 bh = *(const bfx8*)(pBh + boff);
        bfx8 bl = *(const bfx8*)(pBl + boff);
#pragma unroll
        for (int rt = 0; rt < 2; rt++) {
          acc[rt][ct] = MFMA16(ah[rt], bh, acc[rt][ct]);
          acc[rt][ct] = MFMA16(al[rt], bh, acc[rt][ct]);
          acc[rt][ct] = MFMA16(ah[rt], bl, acc[rt][ct]);
        }
      }
    }
  }
#pragma unroll
  for (int rt = 0; rt < 2; rt++)
#pragma unroll
    for (int ct = 0; ct < 4; ct++)
#pragma unroll
      for (int j = 0; j < 4; j++) {
        int r = row0 + rgrp * 32 + rt * 16 + kg * 4 + j;
        int cc = col0 + cgrp * 64 + ct * 16 + l15;
        float b = (cc < 512) ? bias[cc] : bias2[cc - 512];
        C[(size_t)r * N + cc] = acc[rt][ct][j] + b;
      }
}

// ---------- mf GEMM with fused vdf: x1 = relu([pc_feat | vdf] @ mf_w2 + b2) ----------
__global__ __launch_bounds__(256) void k_mgemm_mf(const float* __restrict__ A,
                                                  const float* __restrict__ vol,
                                                  const float* __restrict__ dist,
                                                  const float* __restrict__ ec,
                                                  const float* __restrict__ w1,
                                                  const float* __restrict__ b1,
                                                  const ushort_t* __restrict__ Bh,
                                                  const ushort_t* __restrict__ Bl,
                                                  const float* __restrict__ bias,
                                                  float* __restrict__ C) {
  const int M = 2048, N = 512, K = 1024;
  __shared__ ushort_t sAh[4096], sAl[4096], sBh[4096], sBl[4096];  // 32 KB
  char* pAh = (char*)sAh; char* pAl = (char*)sAl;
  char* pBh = (char*)sBh; char* pBl = (char*)sBl;
  const int t = threadIdx.x;
  const int w = t >> 6, lane = t & 63, l15 = lane & 15, kg = lane >> 4;
  const int row0 = blockIdx.x * 64, col0 = blockIdx.y * 64;
  const int sr = t >> 2;
  const int sc = (t & 3) * 16;
  const int sswz = (sr & 7) << 4;
  const int sbase = sr * 128 + sc * 2;
  f32x4 acc[4];
#pragma unroll
  for (int ct = 0; ct < 4; ct++) acc[ct] = (f32x4){0.f, 0.f, 0.f, 0.f};

  const int r = row0 + sr;
  const float v0 = vol[r], d0 = dist[r], e0 = ec[r];

  for (int kb = 0; kb < K; kb += 64) {
    __syncthreads();
    {
      const int kc = kb + sc;  // 16-run never straddles the 512 boundary
      float4 a0, a1, a2, a3;
      if (kc < 512) {
        const float* Ap = A + (size_t)r * 1024 + kc;
        a0 = *(const float4*)(Ap);
        a1 = *(const float4*)(Ap + 4);
        a2 = *(const float4*)(Ap + 8);
        a3 = *(const float4*)(Ap + 12);
      } else {
        const int j = kc - 512;
        float tmp[16];
#pragma unroll
        for (int i = 0; i < 16; i++) {
          float v = v0 * w1[j + i] + d0 * w1[512 + j + i] + e0 * w1[1024 + j + i] + b1[j + i];
          tmp[i] = fmaxf(v, 0.0f);
        }
        a0 = make_float4(tmp[0], tmp[1], tmp[2], tmp[3]);
        a1 = make_float4(tmp[4], tmp[5], tmp[6], tmp[7]);
        a2 = make_float4(tmp[8], tmp[9], tmp[10], tmp[11]);
        a3 = make_float4(tmp[12], tmp[13], tmp[14], tmp[15]);
      }
      union { bfx8 v; unsigned u[4]; } vh0, vh1, vl0, vl1;
      split2pk(a0.x, a0.y, vh0.u[0], vl0.u[0]);
      split2pk(a0.z, a0.w, vh0.u[1], vl0.u[1]);
      split2pk(a1.x, a1.y, vh0.u[2], vl0.u[2]);
      split2pk(a1.z, a1.w, vh0.u[3], vl0.u[3]);
      split2pk(a2.x, a2.y, vh1.u[0], vl1.u[0]);
      split2pk(a2.z, a2.w, vh1.u[1], vl1.u[1]);
      split2pk(a3.x, a3.y, vh1.u[2], vl1.u[2]);
      split2pk(a3.z, a3.w, vh1.u[3], vl1.u[3]);
      *(bfx8*)(pAh + ((sbase) ^ sswz)) = vh0.v;
      *(bfx8*)(pAh + ((sbase + 16) ^ sswz)) = vh1.v;
      *(bfx8*)(pAl + ((sbase) ^ sswz)) = vl0.v;
      *(bfx8*)(pAl + ((sbase + 16) ^ sswz)) = vl1.v;
    }
    {
      const ushort_t* Bph = Bh + (size_t)(col0 + sr) * K + kb + sc;
      const ushort_t* Bpl = Bl + (size_t)(col0 + sr) * K + kb + sc;
      bfx8 b0 = *(const bfx8*)Bph, b1v = *(const bfx8*)(Bph + 8);
      bfx8 c0v = *(const bfx8*)Bpl, c1v = *(const bfx8*)(Bpl + 8);
      *(bfx8*)(pBh + ((sbase) ^ sswz)) = b0;
      *(bfx8*)(pBh + ((sbase + 16) ^ sswz)) = b1v;
      *(bfx8*)(pBl + ((sbase) ^ sswz)) = c0v;
      *(bfx8*)(pBl + ((sbase + 16) ^ sswz)) = c1v;
    }
    __syncthreads();
#pragma unroll
    for (int ks = 0; ks < 2; ks++) {
      const int arow = w * 16 + l15;
      const int k2 = (ks * 32 + kg * 8) * 2;
      const int aoff = (arow * 128 + k2) ^ ((arow & 7) << 4);
      bfx8 ah = *(const bfx8*)(pAh + aoff);
      bfx8 al = *(const bfx8*)(pAl + aoff);
#pragma unroll
      for (int ct = 0; ct < 4; ct++) {
        const int bcol = ct * 16 + l15;
        const int boff = (bcol * 128 + k2) ^ ((bcol & 7) << 4);
        bfx8 bh = *(const bfx8*)(pBh + boff);
        bfx8 bl = *(const bfx8*)(pBl + boff);
        acc[ct] = MFMA16(ah, bh, acc[ct]);
        acc[ct] = MFMA16(al, bh, acc[ct]);
        acc[ct] = MFMA16(ah, bl, acc[ct]);
      }
    }
  }
#pragma unroll
  for (int ct = 0; ct < 4; ct++)
#pragma unroll
    for (int j = 0; j < 4; j++) {
      int rr = row0 + w * 16 + kg * 4 + j;
      int cc = col0 + ct * 16 + l15;
      float v = acc[ct][j] + bias[cc];
      C[(size_t)rr * N + cc] = fmaxf(v, 0.0f);
    }
}

// ---------- generic f32 GEMM (small classifier layer + fallback) ----------
template <int ACT>
__global__ __launch_bounds__(256) void k_gemm(const float* __restrict__ A,
                                              const float* __restrict__ W,
                                              const float* __restrict__ bias,
                                              float* __restrict__ C, int M, int N, int K,
                                              int ldc, int cof) {
  __shared__ float sA[64][17];
  __shared__ float sW[16][64];
  const int t = threadIdx.x;
  const int row0 = blockIdx.x * 64, col0 = blockIdx.y * 64;
  const int tr = t >> 4, tc = t & 15;
  const int la_r = t >> 2, la_c = (t & 3) * 4;
  const int lw_r = t >> 4, lw_c = (t & 15) * 4;
  float acc[4][4] = {};
  for (int kb = 0; kb < K; kb += 16) {
    __syncthreads();
    float4 av = *(const float4*)(A + (size_t)(row0 + la_r) * K + kb + la_c);
    sA[la_r][la_c + 0] = av.x; sA[la_r][la_c + 1] = av.y;
    sA[la_r][la_c + 2] = av.z; sA[la_r][la_c + 3] = av.w;
    float4 wv = *(const float4*)(W + (size_t)(kb + lw_r) * N + col0 + lw_c);
    *(float4*)&sW[lw_r][lw_c] = wv;
    __syncthreads();
#pragma unroll
    for (int kk = 0; kk < 16; kk++) {
      float a0 = sA[tr * 4 + 0][kk], a1 = sA[tr * 4 + 1][kk];
      float a2 = sA[tr * 4 + 2][kk], a3 = sA[tr * 4 + 3][kk];
      float4 w4 = *(const float4*)&sW[kk][tc * 4];
      acc[0][0] = fmaf(a0, w4.x, acc[0][0]); acc[0][1] = fmaf(a0, w4.y, acc[0][1]);
      acc[0][2] = fmaf(a0, w4.z, acc[0][2]); acc[0][3] = fmaf(a0, w4.w, acc[0][3]);
      acc[1][0] = fmaf(a1, w4.x, acc[1][0]); acc[1][1] = fmaf(a1, w4.y, acc[1][1]);
      acc[1][2] = fmaf(a1, w4.z, acc[1][2]); acc[1][3] = fmaf(a1, w4.w, acc[1][3]);
      acc[2][0] = fmaf(a2, w4.x, acc[2][0]); acc[2][1] = fmaf(a2, w4.y, acc[2][1]);
      acc[2][2] = fmaf(a2, w4.z, acc[2][2]); acc[2][3] = fmaf(a2, w4.w, acc[2][3]);
      acc[3][0] = fmaf(a3, w4.x, acc[3][0]); acc[3][1] = fmaf(a3, w4.y, acc[3][1]);
      acc[3][2] = fmaf(a3, w4.z, acc[3][2]); acc[3][3] = fmaf(a3, w4.w, acc[3][3]);
    }
  }
#pragma unroll
  for (int i = 0; i < 4; i++) {
    int r = row0 + tr * 4 + i;
#pragma unroll
    for (int j = 0; j < 4; j++) {
      int c = col0 + tc * 4 + j;
      float v = acc[i][j] + bias[c];
      if (ACT == 1) v = fmaxf(v, 0.0f);
      C[(size_t)r * ldc + cof + c] = v;
    }
  }
}

// ---------- fused GATv2 per node: scores + online softmax + aggregate ----------
// xlr packed [2048][1024]: cols 0-511 = xl, 512-1023 = xr.
template <int ACT>
__global__ __launch_bounds__(256) void k_gat(
    const float* __restrict__ xlr, const float* __restrict__ att,
    const int* __restrict__ row_ptr, const int* __restrict__ edge_list,
    const int* __restrict__ ei, const float* __restrict__ bias,
    float* __restrict__ out) {
  __shared__ float sXr[512];
  __shared__ float sPb[32][8];
  __shared__ int sSrc[32];
  __shared__ float sM[8], sD[8], sScale[8];
  const int n = blockIdx.x, t = threadIdx.x;
  const int wv = t >> 6, l = t & 63;
  float attr[8];
#pragma unroll
  for (int h = 0; h < 8; h++) attr[h] = att[h * 64 + l];
  for (int i = t; i < 512; i += 256) sXr[i] = xlr[(size_t)n * 1024 + 512 + i];
  if (t < 8) { sM[t] = -1e30f; sD[t] = 0.f; }
  const int f0 = t, f1 = t + 256;
  const int h0 = f0 >> 6, h1 = f1 >> 6;
  float acc0 = 0.f, acc1 = 0.f;
  const int beg = row_ptr[n], end = row_ptr[n + 1];
  __syncthreads();
  for (int b = beg; b < end; b += 32) {
    const int cnt = min(32, end - b);
    // phase A: per-edge scores (one wave per edge)
    for (int i = wv; i < cnt; i += 4) {
      const int e = edge_list[b + i];
      const int s = e_src(ei, e);
      const float* xs = xlr + (size_t)s * 1024;
      float ps[8];
#pragma unroll
      for (int h = 0; h < 8; h++) {
        float v = xs[h * 64 + l] + sXr[h * 64 + l];
        v = v > 0.f ? v : 0.2f * v;  // leaky_relu(0.2)
        ps[h] = v * attr[h];
      }
#pragma unroll
      for (int off = 1; off < 64; off <<= 1)
#pragma unroll
        for (int h = 0; h < 8; h++) ps[h] += __shfl_xor(ps[h], off);
      if (l == 0) {
        sSrc[i] = s;
#pragma unroll
        for (int h = 0; h < 8; h++) sPb[i][h] = ps[h];
      }
    }
    __syncthreads();
    // phase B: online softmax bookkeeping (8 threads, one per head)
    if (t < 8) {
      float m = sM[t];
      for (int i = 0; i < cnt; i++) m = fmaxf(m, sPb[i][t]);
      float scale = expf(sM[t] - m);
      float d = sD[t] * scale;
      for (int i = 0; i < cnt; i++) {
        float p = expf(sPb[i][t] - m);
        sPb[i][t] = p;
        d += p;
      }
      sM[t] = m; sD[t] = d; sScale[t] = scale;
    }
    __syncthreads();
    // phase C: rescale + accumulate
    acc0 *= sScale[h0];
    acc1 *= sScale[h1];
    for (int i = 0; i < cnt; i++) {
      const float* xs = xlr + (size_t)sSrc[i] * 1024;
      acc0 = fmaf(sPb[i][h0], xs[f0], acc0);
      acc1 = fmaf(sPb[i][h1], xs[f1], acc1);
    }
    __syncthreads();  // protect sPb/sM/sSrc before next batch
  }
  float v0 = acc0 / sD[h0] + bias[f0];
  float v1 = acc1 / sD[h1] + bias[f1];
  if (ACT == 1) { v0 = fmaxf(v0, 0.f); v1 = fmaxf(v1, 0.f); }
  out[(size_t)n * 512 + f0] = v0;
  out[(size_t)n * 512 + f1] = v1;
}

// ---------- logits + BCE loss + per-graph argmax hits ----------
__global__ __launch_bounds__(1024) void k_final(const float* __restrict__ hc2,
                                                const float* __restrict__ w3,
                                                const float* __restrict__ b3,
                                                const float* __restrict__ y,
                                                float* __restrict__ out) {
  __shared__ float sL[2048];
  __shared__ float sRed[1024];
  __shared__ float sW[64];
  const int t = threadIdx.x;
  if (t < 64) sW[t] = w3[t];
  __syncthreads();
  float lp = 0.0f;
  for (int n = t; n < 2048; n += 1024) {
    const float4* r = (const float4*)(hc2 + (size_t)n * 64);
    float a = 0.0f;
#pragma unroll
    for (int k = 0; k < 16; k++) {
      float4 v = r[k];
      a += v.x * sW[4 * k] + v.y * sW[4 * k + 1] + v.z * sW[4 * k + 2] + v.w * sW[4 * k + 3];
    }
    a += b3[0];
    sL[n] = a;
    lp += fmaxf(a, 0.0f) - a * y[n] + log1pf(expf(-fabsf(a)));
  }
  sRed[t] = lp;
  __syncthreads();
  for (int off = 512; off > 0; off >>= 1) {
    if (t < off) sRed[t] += sRed[t + off];
    __syncthreads();
  }
  if (t == 0) out[0] = sRed[0] * (1.0f / 2048.0f);
  __syncthreads();
  float hit = 0.0f;
  if (t < 64) {
    const int base = t * NPG;
    float bl = sL[base]; int bi = 0;
    float by = y[base];  int byi = 0;
    for (int i = 1; i < NPG - 1; i++) {  // [:, :-1] -> 31 entries, first-max tie rule
      float v = sL[base + i];
      if (v > bl) { bl = v; bi = i; }
      float w = y[base + i];
      if (w > by) { by = w; byi = i; }
    }
    hit = (bi == byi) ? 1.0f : 0.0f;
  }
  __syncthreads();
  sRed[t] = hit;
  __syncthreads();
  for (int off = 512; off > 0; off >>= 1) {
    if (t < off) sRed[t] += sRed[t + off];
    __syncthreads();
  }
  if (t == 0) out[1] = sRed[0] * (1.0f / 64.0f);
}

// ---------- workspace layout (float units) ----------
constexpr size_t OFF_XCAT = 0;                                  // [2048,1024] (also xl|xr)
constexpr size_t OFF_X1   = OFF_XCAT + (size_t)2048 * 1024;     // [2048,512]
constexpr size_t OFF_XL   = OFF_X1 + (size_t)2048 * 512;        // (fallback only)
constexpr size_t OFF_XR   = OFF_XL + (size_t)2048 * 512;
constexpr size_t OFF_G1   = OFF_XR + (size_t)2048 * 512;
constexpr size_t OFF_G2   = OFF_G1 + (size_t)2048 * 512;
constexpr size_t OFF_HC1  = OFF_G2 + (size_t)2048 * 512;        // [2048,64]
constexpr size_t OFF_HC2  = OFF_HC1 + (size_t)2048 * 64;
constexpr size_t OFF_SC   = OFF_HC2 + (size_t)2048 * 64;        // (legacy, unused)
constexpr size_t OFF_P    = OFF_SC + (size_t)N_EDGE_TOT * 8;
constexpr size_t OFF_M    = OFF_P + (size_t)N_EDGE_TOT * 8;
constexpr size_t OFF_DEN  = OFF_M + (size_t)2048 * 8;
constexpr size_t OFF_RP   = OFF_DEN + (size_t)2048 * 8;         // int [2052]
constexpr size_t OFF_CNT  = OFF_RP + 2052;                      // int [2048]
constexpr size_t OFF_EL   = OFF_CNT + 2048;                     // int [34816]
constexpr size_t OFF_USH  = OFF_EL + 34816;                     // ushort regions (16B aligned)

constexpr size_t WS_NEED_FULL = (OFF_USH + (U_END + 1) / 2) * sizeof(float);

extern "C" void kernel_launch(void* const* d_in, const int* in_sizes, int n_in,
                              void* d_out, int out_size, void* d_ws, size_t ws_size,
                              hipStream_t stream) {
  const float* pcd   = (const float*)d_in[0];
  const float* vol   = (const float*)d_in[1];
  const float* dist  = (const float*)d_in[2];
  const float* ecnt  = (const float*)d_in[3];
  const float* y     = (const float*)d_in[4];
  const float* pn_w1 = (const float*)d_in[5];
  const float* pn_w2 = (const float*)d_in[6];
  const float* pn_w3 = (const float*)d_in[7];
  const float* pn_w4 = (const float*)d_in[8];
  const float* pn_w5 = (const float*)d_in[9];
  const float* mf_w1 = (const float*)d_in[10];
  const float* mf_b1 = (const float*)d_in[11];
  const float* mf_w2 = (const float*)d_in[12];
  const float* mf_b2 = (const float*)d_in[13];
  const float* g1_wl = (const float*)d_in[14];
  const float* g1_bl = (const float*)d_in[15];
  const float* g1_wr = (const float*)d_in[16];
  const float* g1_br = (const float*)d_in[17];
  const float* g1_at = (const float*)d_in[18];
  const float* g1_bi = (const float*)d_in[19];
  const float* g2_wl = (const float*)d_in[20];
  const float* g2_bl = (const float*)d_in[21];
  const float* g2_wr = (const float*)d_in[22];
  const float* g2_br = (const float*)d_in[23];
  const float* g2_at = (const float*)d_in[24];
  const float* g2_bi = (const float*)d_in[25];
  const float* cl_w1 = (const float*)d_in[26];
  const float* cl_b1 = (const float*)d_in[27];
  const float* cl_w2 = (const float*)d_in[28];
  const float* cl_b2 = (const float*)d_in[29];
  const float* cl_w3 = (const float*)d_in[30];
  const float* cl_b3 = (const float*)d_in[31];
  const int*   ei    = (const int*)d_in[32];
  float* out = (float*)d_out;
  float* ws  = (float*)d_ws;

  float* xcat = ws + OFF_XCAT;   // pointnet output; later reused as xl|xr
  float* x1   = ws + OFF_X1;
  float* g1o  = ws + OFF_G1;
  float* g2o  = ws + OFF_G2;
  float* hc1  = ws + OFF_HC1;
  float* hc2  = ws + OFF_HC2;
  int* rp     = (int*)(ws + OFF_RP);
  int* cnt    = (int*)(ws + OFF_CNT);
  int* el     = (int*)(ws + OFF_EL);
  ushort_t* ush = (ushort_t*)(ws + OFF_USH);

  const bool full = (ws_size >= WS_NEED_FULL);

  // --- build CSR by dst (shared by both GAT layers) ---
  hipMemsetAsync(cnt, 0, 2048 * sizeof(int), stream);
  k_hist<<<(N_EDGE_TOT + 255) / 256, 256, 0, stream>>>(ei, cnt);
  k_scan<<<1, 256, 0, stream>>>(cnt, rp);  // also re-zeros cnt for k_scatter
  k_scatter<<<(N_EDGE_TOT + 255) / 256, 256, 0, stream>>>(ei, rp, cnt, el);

  // --- weight prep: ALL splits in one launch ---
  k_split_all<<<412, 256, 0, stream>>>(pn_w2, pn_w3, pn_w4, pn_w5, mf_w2,
                                       g1_wl, g1_wr, g2_wl, g2_wr, cl_w1,
                                       ush, full ? 1 : 0);

  // --- PointNet + multi-feature (vdf fused into mf GEMM) ---
  k_pointnet<<<N_NODES, 512, 0, stream>>>(pcd, pn_w1,
      ush + U_W2H, ush + U_W2L, ush + U_W3H, ush + U_W3L,
      ush + U_W4H, ush + U_W4L, ush + U_W5H, ush + U_W5L, xcat);
  if (full) {
    k_mgemm_mf<<<dim3(32, 8), 256, 0, stream>>>(xcat, vol, dist, ecnt, mf_w1, mf_b1,
                                                ush + U_MFH, ush + U_MFL, mf_b2, x1);
  } else {
    k_vdf<<<2048 * 512 / 256, 256, 0, stream>>>(vol, dist, ecnt, mf_w1, mf_b1, xcat);
    k_gemm<1><<<dim3(32, 8), 256, 0, stream>>>(xcat, mf_w2, mf_b2, x1, 2048, 512, 1024, 512, 0);
  }

  // --- GAT layers (merged wl|wr transform, 64x128 tiles) ---
  if (full) {
    k_mgemm2<<<dim3(32, 8), 256, 0, stream>>>(x1, ush + U_G1H, ush + U_G1L, g1_bl, g1_br, xcat, 2048, 1024, 512);
    k_gat<1><<<N_NODES, 256, 0, stream>>>(xcat, g1_at, rp, el, ei, g1_bi, g1o);
    k_mgemm2<<<dim3(32, 8), 256, 0, stream>>>(g1o, ush + U_G2H, ush + U_G2L, g2_bl, g2_br, xcat, 2048, 1024, 512);
    k_gat<0><<<N_NODES, 256, 0, stream>>>(xcat, g2_at, rp, el, ei, g2_bi, g2o);
    k_mgemm<1><<<dim3(32, 1), 256, 0, stream>>>(g2o, ush + U_CL1H, ush + U_CL1L, cl_b1, cl_b1, hc1, 2048, 64, 512);
  } else {
    k_gemm<0><<<dim3(32, 8), 256, 0, stream>>>(x1, g1_wl, g1_bl, xcat, 2048, 512, 512, 1024, 0);
    k_gemm<0><<<dim3(32, 8), 256, 0, stream>>>(x1, g1_wr, g1_br, xcat, 2048, 512, 512, 1024, 512);
    k_gat<1><<<N_NODES, 256, 0, stream>>>(xcat, g1_at, rp, el, ei, g1_bi, g1o);
    k_gemm<0><<<dim3(32, 8), 256, 0, stream>>>(g1o, g2_wl, g2_bl, xcat, 2048, 512, 512, 1024, 0);
    k_gemm<0><<<dim3(32, 8), 256, 0, stream>>>(g1o, g2_wr, g2_br, xcat, 2048, 512, 512, 1024, 512);
    k_gat<0><<<N_NODES, 256, 0, stream>>>(xcat, g2_at, rp, el, ei, g2_bi, g2o);
    k_gemm<1><<<dim3(32, 1), 256, 0, stream>>>(g2o, cl_w1, cl_b1, hc1, 2048, 64, 512, 64, 0);
  }
  k_gemm<1><<<dim3(32, 1), 256, 0, stream>>>(hc1, cl_w2, cl_b2, hc2, 2048, 64, 64, 64, 0);
  k_final<<<1, 1024, 0, stream>>>(hc2, cl_w3, cl_b3, y, out);
}

// Round 12
// 432.046 us; speedup vs baseline: 1.0253x; 1.0253x over previous
//
#include <hip/hip_runtime.h>
#include <cstdint>
#include <cstddef>

#define N_NODES 2048
#define N_PTS 256
#define N_EDGE 32768
#define N_EDGE_TOT (N_EDGE + N_NODES)  // 34816, with self-loops appended
#define NPG 32                          // nodes per graph (2048/64)

typedef __attribute__((ext_vector_type(8))) short bfx8;
typedef __attribute__((ext_vector_type(4))) float f32x4;
typedef unsigned short ushort_t;

#define MFMA16(a, b, c) __builtin_amdgcn_mfma_f32_16x16x32_bf16(a, b, c, 0, 0, 0)

// ---------- helpers ----------
__device__ inline int e_src(const int* ei, int e) { return e < N_EDGE ? ei[e] : e - N_EDGE; }
__device__ inline int e_dst(const int* ei, int e) { return e < N_EDGE ? ei[N_EDGE + e] : e - N_EDGE; }

// HW packed f32->bf16 (RTNE): dst[15:0]=bf16(a), dst[31:16]=bf16(b).
__device__ inline unsigned cvtpk_bf16(float a, float b) {
  unsigned r;
  asm("v_cvt_pk_bf16_f32 %0, %1, %2" : "=v"(r) : "v"(a), "v"(b));
  return r;
}
// split 2 floats -> packed hi pair + packed lo pair (residuals exact)
__device__ inline void split2pk(float a, float b, unsigned& hp, unsigned& lp) {
  hp = cvtpk_bf16(a, b);
  float ha = __uint_as_float(hp << 16);
  float hb = __uint_as_float(hp & 0xffff0000u);
  lp = cvtpk_bf16(a - ha, b - hb);
}

// ---------- graph build: CSR of in-edges grouped by dst ----------
__global__ void k_hist(const int* __restrict__ ei, int* __restrict__ cnt) {
  int e = blockIdx.x * 256 + threadIdx.x;
  if (e >= N_EDGE_TOT) return;
  atomicAdd(&cnt[e_dst(ei, e)], 1);
}

// scan + re-zero cnt (folds the second memset; replay-safe: pre-hist memset remains)
__global__ __launch_bounds__(256) void k_scan(int* __restrict__ cnt, int* __restrict__ row_ptr) {
  __shared__ int sS[256];
  const int t = threadIdx.x;
  int v[8]; int s = 0;
#pragma unroll
  for (int i = 0; i < 8; i++) { v[i] = cnt[t * 8 + i]; s += v[i]; }
#pragma unroll
  for (int i = 0; i < 8; i++) cnt[t * 8 + i] = 0;  // cnt reused as cursor by k_scatter
  sS[t] = s;
  __syncthreads();
  for (int off = 1; off < 256; off <<= 1) {
    int x = 0;
    if (t >= off) x = sS[t - off];
    __syncthreads();
    sS[t] += x;
    __syncthreads();
  }
  int run = sS[t] - s;  // exclusive prefix
#pragma unroll
  for (int i = 0; i < 8; i++) { row_ptr[t * 8 + i] = run; run += v[i]; }
  if (t == 255) row_ptr[2048] = run;
}

__global__ void k_scatter(const int* __restrict__ ei, const int* __restrict__ row_ptr,
                          int* __restrict__ cur, int* __restrict__ edge_list) {
  int e = blockIdx.x * 256 + threadIdx.x;
  if (e >= N_EDGE_TOT) return;
  int d = e_dst(ei, e);
  int pos = row_ptr[d] + atomicAdd(&cur[d], 1);
  edge_list[pos] = e;
}

// ---------- tiled weight prep: [K][N] -> [N][K], split hi/lo bf16, coalesced ----------
__device__ inline void split_tile(const float* __restrict__ src, ushort_t* __restrict__ dh,
                                  ushort_t* __restrict__ dl, int K, int N,
                                  int k0, int n0, int t) {
  __shared__ float sT[64][65];
  const int lr = t >> 4, lc = (t & 15) * 4;
#pragma unroll
  for (int p = 0; p < 4; p++) {
    int k = lr + p * 16;
    float4 v = *(const float4*)(src + (size_t)(k0 + k) * N + n0 + lc);
    sT[k][lc] = v.x; sT[k][lc + 1] = v.y; sT[k][lc + 2] = v.z; sT[k][lc + 3] = v.w;
  }
  __syncthreads();
  const int wr = t >> 4, wc = (t & 15) * 4;
#pragma unroll
  for (int p = 0; p < 4; p++) {
    int nrow = wr + p * 16;
    uint2 uh, ul;
    split2pk(sT[wc + 0][nrow], sT[wc + 1][nrow], uh.x, ul.x);
    split2pk(sT[wc + 2][nrow], sT[wc + 3][nrow], uh.y, ul.y);
    *(uint2*)(dh + (size_t)(n0 + nrow) * K + k0 + wc) = uh;
    *(uint2*)(dl + (size_t)(n0 + nrow) * K + k0 + wc) = ul;
  }
}

// ushort sub-offsets (units: ushorts, from OFF_USH)
constexpr size_t U_W2H = 0,       U_W2L = 4096;
constexpr size_t U_W3H = 8192,    U_W3L = 12288;
constexpr size_t U_W4H = 16384,   U_W4L = 24576;
constexpr size_t U_W5H = 32768,   U_W5L = 98304;   // end 163840
constexpr size_t U_MFH = 163840,  U_MFL = 688128;  // 1024x512, end 1212416
constexpr size_t U_G1H = 1212416;                   // [1024][512] hi (wl|wr)
constexpr size_t U_G1L = 1736704;                   // [1024][512] lo
constexpr size_t U_G2H = 2260992;
constexpr size_t U_G2L = 2785280;                   // end 3309568
constexpr size_t U_CL1H = 3309568, U_CL1L = 3342336;  // end 3375104
constexpr size_t U_END  = 3375104;

// ALL weight splits in one launch (412 blocks):
// z 0..19: pointnet (w2,w3,w4,w5); z 20..147: mf_w2; z 148..403: GAT wl/wr x2;
// z 404..411: cl_w1. Non-PN regions gated by `full`.
__global__ __launch_bounds__(256) void k_split_all(
    const float* __restrict__ w2, const float* __restrict__ w3,
    const float* __restrict__ w4, const float* __restrict__ w5,
    const float* __restrict__ mfw, const float* __restrict__ g1l,
    const float* __restrict__ g1r, const float* __restrict__ g2l,
    const float* __restrict__ g2r, const float* __restrict__ clw,
    ushort_t* __restrict__ ush, int full) {
  const int z = blockIdx.x;
  const int t = threadIdx.x;
  if (z < 20) {
    const float* src; ushort_t* dh; ushort_t* dl; int K, N, k0, n0;
    if (z == 0)      { src = w2; dh = ush + U_W2H; dl = ush + U_W2L; K = 64;  N = 64;  k0 = 0; n0 = 0; }
    else if (z == 1) { src = w3; dh = ush + U_W3H; dl = ush + U_W3L; K = 64;  N = 64;  k0 = 0; n0 = 0; }
    else if (z < 4)  { src = w4; dh = ush + U_W4H; dl = ush + U_W4L; K = 64;  N = 128; k0 = 0; n0 = (z - 2) * 64; }
    else { int i = z - 4; src = w5; dh = ush + U_W5H; dl = ush + U_W5L; K = 128; N = 512;
           k0 = (i >> 3) * 64; n0 = (i & 7) * 64; }
    split_tile(src, dh, dl, K, N, k0, n0, t);
  } else if (!full) {
    return;
  } else if (z < 148) {
    int i = z - 20;  // 16 k-tiles x 8 n-tiles
    split_tile(mfw, ush + U_MFH, ush + U_MFL, 1024, 512, (i >> 3) * 64, (i & 7) * 64, t);
  } else if (z < 404) {
    int i = z - 148;
    int m = i >> 6, tile = i & 63;
    const float* src = (m == 0) ? g1l : (m == 1) ? g1r : (m == 2) ? g2l : g2r;
    ushort_t* dh = ush + U_G1H + (size_t)(m >> 1) * 1048576 + (size_t)(m & 1) * 262144;
    ushort_t* dl = dh + 524288;
    split_tile(src, dh, dl, 512, 512, (tile >> 3) * 64, (tile & 7) * 64, t);
  } else {
    int i = z - 404;  // 8 k-tiles x 1
    split_tile(clw, ush + U_CL1H, ush + U_CL1L, 512, 64, i * 64, 0, t);
  }
}

// ---------- PointNet fused, split-bf16 MFMA (3-pass), LDS-resident ----------
// ROUND-2 STRUCTURE (register-safe: VGPR 96, zero spill) + cvt_pk-based splits.
// FROZEN: restructures spill (rounds 4/6); barrier cuts are neutral (round 8).
// Measured 908 TF-equiv = the plain-HIP 2-barrier-structure ceiling (m103: 912).
__global__ __launch_bounds__(512, 2) void k_pointnet(
    const float* __restrict__ pcd, const float* __restrict__ w1,
    const ushort_t* __restrict__ w2th, const ushort_t* __restrict__ w2tl,
    const ushort_t* __restrict__ w3th, const ushort_t* __restrict__ w3tl,
    const ushort_t* __restrict__ w4th, const ushort_t* __restrict__ w4tl,
    const ushort_t* __restrict__ w5th, const ushort_t* __restrict__ w5tl,
    float* __restrict__ xcat) {
  __shared__ ushort_t sH4H[256 * 128];  // 64 KB, swizzled [row][128]
  __shared__ ushort_t sH4L[256 * 128];  // 64 KB
  __shared__ ushort_t sBAH[32 * 64];    // 4 KB ping
  __shared__ ushort_t sBAL[32 * 64];
  __shared__ ushort_t sBBH[32 * 64];    // 4 KB pong
  __shared__ ushort_t sBBL[32 * 64];
  __shared__ float sP[256 * 3];
  __shared__ float sW1[3 * 64];

  char* H4H = (char*)sH4H; char* H4L = (char*)sH4L;
  char* BAH = (char*)sBAH; char* BAL = (char*)sBAL;
  char* BBH = (char*)sBBH; char* BBL = (char*)sBBL;

  const int t = threadIdx.x;
  const int node = blockIdx.x;
  const int w = t >> 6;
  const int lane = t & 63;
  const int l15 = lane & 15;
  const int kg = lane >> 4;  // 0..3

  // stage pcd + w1
  for (int i = t; i < 768; i += 512) sP[i] = pcd[(size_t)node * 768 + i];
  for (int i = t; i < 192; i += 512) sW1[i] = w1[i];

  // cache per-wave B-fragments for L2-L4 in VGPRs (loaded once)
  const int rt14 = w >> 2;  // 0..1
  const int ct14 = w & 3;   // 0..3
  bfx8 b2h[2], b2l[2], b3h[2], b3l[2], b4h[2][2], b4l[2][2];
#pragma unroll
  for (int ks = 0; ks < 2; ks++) {
    {
      int col = ct14 * 16 + l15;
      int k = ks * 32 + kg * 8;
      b2h[ks] = *(const bfx8*)(w2th + col * 64 + k);
      b2l[ks] = *(const bfx8*)(w2tl + col * 64 + k);
      b3h[ks] = *(const bfx8*)(w3th + col * 64 + k);
      b3l[ks] = *(const bfx8*)(w3tl + col * 64 + k);
    }
#pragma unroll
    for (int u = 0; u < 2; u++) {
      int col = (ct14 * 2 + u) * 16 + l15;
      int k = ks * 32 + kg * 8;
      b4h[u][ks] = *(const bfx8*)(w4th + col * 64 + k);
      b4l[u][ks] = *(const bfx8*)(w4tl + col * 64 + k);
    }
  }
  __syncthreads();

  // L1 thread mapping (all 512 threads): 32 rows x 64 cols
  const int l1r = t >> 4, l1c = t & 15;

  // ---------------- phase 1: L1-L4 over 8 chunks of 32 points ----------------
  // prologue: L1(0) -> BA
  {
    const float* p = &sP[(0 * 32 + l1r) * 3];
    float p0 = p[0], p1 = p[1], p2 = p[2];
    float vv[4];
#pragma unroll
    for (int j = 0; j < 4; j++) {
      int col = l1c * 4 + j;
      vv[j] = fmaxf(fmaf(p0, sW1[col], fmaf(p1, sW1[64 + col], p2 * sW1[128 + col])), 0.0f);
    }
    unsigned hp0, lp0, hp1, lp1;
    split2pk(vv[0], vv[1], hp0, lp0);
    split2pk(vv[2], vv[3], hp1, lp1);
    int off = (l1r * 128 + l1c * 8) ^ ((l1r & 7) << 4);
    *(unsigned*)(BAH + off) = hp0;
    *(unsigned*)(BAH + off + 4) = hp1;
    *(unsigned*)(BAL + off) = lp0;
    *(unsigned*)(BAL + off + 4) = lp1;
  }
  __syncthreads();

  for (int c = 0; c < 8; c++) {
    // ping-pong roles: A holds this chunk's L1 output
    char* Ah = (c & 1) ? BBH : BAH;
    char* Al = (c & 1) ? BBL : BAL;
    char* Bh = (c & 1) ? BAH : BBH;
    char* Bl = (c & 1) ? BAL : BBL;
    // L2: A -> B
    {
      f32x4 acc = {0.f, 0.f, 0.f, 0.f};
#pragma unroll
      for (int ks = 0; ks < 2; ks++) {
        int row = rt14 * 16 + l15;
        int k0 = ks * 32 + kg * 8;
        int offb = (row * 128 + k0 * 2) ^ ((row & 7) << 4);
        bfx8 ah = *(const bfx8*)(Ah + offb);
        bfx8 al = *(const bfx8*)(Al + offb);
        acc = MFMA16(ah, b2h[ks], acc);
        acc = MFMA16(al, b2h[ks], acc);
        acc = MFMA16(ah, b2l[ks], acc);
      }
      unsigned hp[2], lp[2];
      split2pk(fmaxf(acc[0], 0.f), fmaxf(acc[1], 0.f), hp[0], lp[0]);
      split2pk(fmaxf(acc[2], 0.f), fmaxf(acc[3], 0.f), hp[1], lp[1]);
      const int colb = (ct14 * 16 + l15) * 2;
      const int rowb = rt14 * 16 + kg * 4;
#pragma unroll
      for (int j = 0; j < 4; j++) {
        int row = rowb + j;
        int off = (row * 128 + colb) ^ ((row & 7) << 4);
        *(ushort_t*)(Bh + off) = (ushort_t)(hp[j >> 1] >> ((j & 1) * 16));
        *(ushort_t*)(Bl + off) = (ushort_t)(lp[j >> 1] >> ((j & 1) * 16));
      }
    }
    __syncthreads();
    // L3: B -> A
    {
      f32x4 acc = {0.f, 0.f, 0.f, 0.f};
#pragma unroll
      for (int ks = 0; ks < 2; ks++) {
        int row = rt14 * 16 + l15;
        int k0 = ks * 32 + kg * 8;
        int offb = (row * 128 + k0 * 2) ^ ((row & 7) << 4);
        bfx8 ah = *(const bfx8*)(Bh + offb);
        bfx8 al = *(const bfx8*)(Bl + offb);
        acc = MFMA16(ah, b3h[ks], acc);
        acc = MFMA16(al, b3h[ks], acc);
        acc = MFMA16(ah, b3l[ks], acc);
      }
      unsigned hp[2], lp[2];
      split2pk(fmaxf(acc[0], 0.f), fmaxf(acc[1], 0.f), hp[0], lp[0]);
      split2pk(fmaxf(acc[2], 0.f), fmaxf(acc[3], 0.f), hp[1], lp[1]);
      const int colb = (ct14 * 16 + l15) * 2;
      const int rowb = rt14 * 16 + kg * 4;
#pragma unroll
      for (int j = 0; j < 4; j++) {
        int row = rowb + j;
        int off = (row * 128 + colb) ^ ((row & 7) << 4);
        *(ushort_t*)(Ah + off) = (ushort_t)(hp[j >> 1] >> ((j & 1) * 16));
        *(ushort_t*)(Al + off) = (ushort_t)(lp[j >> 1] >> ((j & 1) * 16));
      }
    }
    __syncthreads();
    // L4: A -> H4 rows [c*32, c*32+32)  (+ L1(c+1) -> B, overlapped)
    {
      f32x4 acc[2];
      acc[0] = (f32x4){0.f, 0.f, 0.f, 0.f};
      acc[1] = (f32x4){0.f, 0.f, 0.f, 0.f};
#pragma unroll
      for (int ks = 0; ks < 2; ks++) {
        int row = rt14 * 16 + l15;
        int k0 = ks * 32 + kg * 8;
        int offb = (row * 128 + k0 * 2) ^ ((row & 7) << 4);
        bfx8 ah = *(const bfx8*)(Ah + offb);
        bfx8 al = *(const bfx8*)(Al + offb);
#pragma unroll
        for (int u = 0; u < 2; u++) {
          acc[u] = MFMA16(ah, b4h[u][ks], acc[u]);
          acc[u] = MFMA16(al, b4h[u][ks], acc[u]);
          acc[u] = MFMA16(ah, b4l[u][ks], acc[u]);
        }
      }
      // L1 for next chunk, writes B (disjoint from A and H4) — VALU overlaps MFMA
      if (c < 7) {
        const float* p = &sP[((c + 1) * 32 + l1r) * 3];
        float p0 = p[0], p1 = p[1], p2 = p[2];
        float vv[4];
#pragma unroll
        for (int j = 0; j < 4; j++) {
          int col = l1c * 4 + j;
          vv[j] = fmaxf(fmaf(p0, sW1[col], fmaf(p1, sW1[64 + col], p2 * sW1[128 + col])), 0.0f);
        }
        unsigned hp0, lp0, hp1, lp1;
        split2pk(vv[0], vv[1], hp0, lp0);
        split2pk(vv[2], vv[3], hp1, lp1);
        int off = (l1r * 128 + l1c * 8) ^ ((l1r & 7) << 4);
        *(unsigned*)(Bh + off) = hp0;
        *(unsigned*)(Bh + off + 4) = hp1;
        *(unsigned*)(Bl + off) = lp0;
        *(unsigned*)(Bl + off + 4) = lp1;
      }
      // H4 write: pair across u (same row, cols 32B apart)
#pragma unroll
      for (int j = 0; j < 4; j++) {
        unsigned hp, lp;
        split2pk(fmaxf(acc[0][j], 0.f), fmaxf(acc[1][j], 0.f), hp, lp);
        int row = c * 32 + rt14 * 16 + kg * 4 + j;
        int col0 = (ct14 * 2) * 16 + l15;      // u=0 feature
        int off0 = (row * 256 + col0 * 2) ^ ((row & 7) << 4);
        int off1 = ((row * 256 + (col0 + 16) * 2)) ^ ((row & 7) << 4);
        *(ushort_t*)(H4H + off0) = (ushort_t)hp;
        *(ushort_t*)(H4H + off1) = (ushort_t)(hp >> 16);
        *(ushort_t*)(H4L + off0) = (ushort_t)lp;
        *(ushort_t*)(H4L + off1) = (ushort_t)(lp >> 16);
      }
    }
    __syncthreads();
  }

  // ---------------- phase 2: L5 (256x512x128) + relu + maxpool ----------------
  __builtin_amdgcn_sched_barrier(0);  // keep b5 loads out of phase 1 (VGPR pressure)
  bfx8 b5h[4][4], b5l[4][4];  // [ks][ct]
  const int c0 = w * 64;
#pragma unroll
  for (int ks = 0; ks < 4; ks++)
#pragma unroll
    for (int ct = 0; ct < 4; ct++) {
      int col = c0 + ct * 16 + l15;
      int k = ks * 32 + kg * 8;
      b5h[ks][ct] = *(const bfx8*)(w5th + col * 128 + k);
      b5l[ks][ct] = *(const bfx8*)(w5tl + col * 128 + k);
    }
  float runmax[4] = {0.f, 0.f, 0.f, 0.f};  // relu => max >= 0
  for (int rc = 0; rc < 8; rc++) {
    f32x4 acc[2][4];
#pragma unroll
    for (int rt = 0; rt < 2; rt++)
#pragma unroll
      for (int ct = 0; ct < 4; ct++) acc[rt][ct] = (f32x4){0.f, 0.f, 0.f, 0.f};
#pragma unroll
    for (int ks = 0; ks < 4; ks++) {
      bfx8 ah[2], al[2];
#pragma unroll
      for (int rt = 0; rt < 2; rt++) {
        int row = rc * 32 + rt * 16 + l15;
        int k0 = ks * 32 + kg * 8;
        int off = (row * 256 + k0 * 2) ^ ((row & 7) << 4);
        ah[rt] = *(const bfx8*)(H4H + off);
        al[rt] = *(const bfx8*)(H4L + off);
      }
#pragma unroll
      for (int ct = 0; ct < 4; ct++)
#pragma unroll
        for (int rt = 0; rt < 2; rt++) {
          acc[rt][ct] = MFMA16(ah[rt], b5h[ks][ct], acc[rt][ct]);
          acc[rt][ct] = MFMA16(al[rt], b5h[ks][ct], acc[rt][ct]);
          acc[rt][ct] = MFMA16(ah[rt], b5l[ks][ct], acc[rt][ct]);
        }
    }
#pragma unroll
    for (int ct = 0; ct < 4; ct++)
#pragma unroll
      for (int rt = 0; rt < 2; rt++)
#pragma unroll
        for (int j = 0; j < 4; j++)
          runmax[ct] = fmaxf(runmax[ct], acc[rt][ct][j]);
  }
#pragma unroll
  for (int ct = 0; ct < 4; ct++) {
    float m = runmax[ct];
    m = fmaxf(m, __shfl_xor(m, 16));
    m = fmaxf(m, __shfl_xor(m, 32));
    if (lane < 16) xcat[(size_t)node * 1024 + c0 + ct * 16 + lane] = m;
  }
}

// ---------- multi-feature MLP part 1 (fallback path only) ----------
__global__ void k_vdf(const float* __restrict__ vol, const float* __restrict__ dist,
                      const float* __restrict__ ec, const float* __restrict__ w1,
                      const float* __restrict__ b1, float* __restrict__ xcat) {
  int idx = blockIdx.x * 256 + threadIdx.x;  // 2048*512
  int n = idx >> 9, j = idx & 511;
  float v = vol[n] * w1[j] + dist[n] * w1[512 + j] + ec[n] * w1[1024 + j] + b1[j];
  xcat[(size_t)n * 1024 + 512 + j] = fmaxf(v, 0.0f);
}

// ---------- split-bf16 MFMA GEMM, 64x64 tile ----------
// bias applies to cols [0,512), bias2 to cols [512,N) (for merged wl|wr GEMMs).
template <int ACT>
__global__ __launch_bounds__(256) void k_mgemm(const float* __restrict__ A,
                                               const ushort_t* __restrict__ Bh,
                                               const ushort_t* __restrict__ Bl,
                                               const float* __restrict__ bias,
                                               const float* __restrict__ bias2,
                                               float* __restrict__ C,
                                               int M, int N, int K) {
  __shared__ ushort_t sAh[4096], sAl[4096], sBh[4096], sBl[4096];  // 32 KB
  char* pAh = (char*)sAh; char* pAl = (char*)sAl;
  char* pBh = (char*)sBh; char* pBl = (char*)sBl;
  const int t = threadIdx.x;
  const int w = t >> 6, lane = t & 63, l15 = lane & 15, kg = lane >> 4;
  const int row0 = blockIdx.x * 64, col0 = blockIdx.y * 64;
  const int sr = t >> 2;          // stage row (A) / col (B), 0..63
  const int sc = (t & 3) * 16;    // stage k offset
  const int sswz = (sr & 7) << 4;
  const int sbase = sr * 128 + sc * 2;
  f32x4 acc[4];
#pragma unroll
  for (int ct = 0; ct < 4; ct++) acc[ct] = (f32x4){0.f, 0.f, 0.f, 0.f};

  for (int kb = 0; kb < K; kb += 64) {
    __syncthreads();
    {
      const float* Ap = A + (size_t)(row0 + sr) * K + kb + sc;
      float4 a0 = *(const float4*)(Ap);
      float4 a1 = *(const float4*)(Ap + 4);
      float4 a2 = *(const float4*)(Ap + 8);
      float4 a3 = *(const float4*)(Ap + 12);
      union { bfx8 v; unsigned u[4]; } vh0, vh1, vl0, vl1;
      split2pk(a0.x, a0.y, vh0.u[0], vl0.u[0]);
      split2pk(a0.z, a0.w, vh0.u[1], vl0.u[1]);
      split2pk(a1.x, a1.y, vh0.u[2], vl0.u[2]);
      split2pk(a1.z, a1.w, vh0.u[3], vl0.u[3]);
      split2pk(a2.x, a2.y, vh1.u[0], vl1.u[0]);
      split2pk(a2.z, a2.w, vh1.u[1], vl1.u[1]);
      split2pk(a3.x, a3.y, vh1.u[2], vl1.u[2]);
      split2pk(a3.z, a3.w, vh1.u[3], vl1.u[3]);
      *(bfx8*)(pAh + ((sbase) ^ sswz)) = vh0.v;
      *(bfx8*)(pAh + ((sbase + 16) ^ sswz)) = vh1.v;
      *(bfx8*)(pAl + ((sbase) ^ sswz)) = vl0.v;
      *(bfx8*)(pAl + ((sbase + 16) ^ sswz)) = vl1.v;
    }
    {
      const ushort_t* Bph = Bh + (size_t)(col0 + sr) * K + kb + sc;
      const ushort_t* Bpl = Bl + (size_t)(col0 + sr) * K + kb + sc;
      bfx8 b0 = *(const bfx8*)Bph, b1 = *(const bfx8*)(Bph + 8);
      bfx8 c0v = *(const bfx8*)Bpl, c1v = *(const bfx8*)(Bpl + 8);
      *(bfx8*)(pBh + ((sbase) ^ sswz)) = b0;
      *(bfx8*)(pBh + ((sbase + 16) ^ sswz)) = b1;
      *(bfx8*)(pBl + ((sbase) ^ sswz)) = c0v;
      *(bfx8*)(pBl + ((sbase + 16) ^ sswz)) = c1v;
    }
    __syncthreads();
#pragma unroll
    for (int ks = 0; ks < 2; ks++) {
      const int arow = w * 16 + l15;
      const int k2 = (ks * 32 + kg * 8) * 2;
      const int aoff = (arow * 128 + k2) ^ ((arow & 7) << 4);
      bfx8 ah = *(const bfx8*)(pAh + aoff);
      bfx8 al = *(const bfx8*)(pAl + aoff);
#pragma unroll
      for (int ct = 0; ct < 4; ct++) {
        const int bcol = ct * 16 + l15;
        const int boff = (bcol * 128 + k2) ^ ((bcol & 7) << 4);
        bfx8 bh = *(const bfx8*)(pBh + boff);
        bfx8 bl = *(const bfx8*)(pBl + boff);
        acc[ct] = MFMA16(ah, bh, acc[ct]);
        acc[ct] = MFMA16(al, bh, acc[ct]);
        acc[ct] = MFMA16(ah, bl, acc[ct]);
      }
    }
  }
#pragma unroll
  for (int ct = 0; ct < 4; ct++)
#pragma unroll
    for (int j = 0; j < 4; j++) {
      int r = row0 + w * 16 + kg * 4 + j;
      int cc = col0 + ct * 16 + l15;
      float b = (cc < 512) ? bias[cc] : bias2[cc - 512];
      float v = acc[ct][j] + b;
      if (ACT == 1) v = fmaxf(v, 0.0f);
      C[(size_t)r * N + cc] = v;
    }
}

// ---------- mf GEMM with fused vdf: x1 = relu([pc_feat | vdf] @ mf_w2 + b2) ----------
__global__ __launch_bounds__(256) void k_mgemm_mf(const float* __restrict__ A,
                                                  const float* __restrict__ vol,
                                                  const float* __restrict__ dist,
                                                  const float* __restrict__ ec,
                                                  const float* __restrict__ w1,
                                                  const float* __restrict__ b1,
                                                  const ushort_t* __restrict__ Bh,
                                                  const ushort_t* __restrict__ Bl,
                                                  const float* __restrict__ bias,
                                                  float* __restrict__ C) {
  const int M = 2048, N = 512, K = 1024;
  __shared__ ushort_t sAh[4096], sAl[4096], sBh[4096], sBl[4096];  // 32 KB
  char* pAh = (char*)sAh; char* pAl = (char*)sAl;
  char* pBh = (char*)sBh; char* pBl = (char*)sBl;
  const int t = threadIdx.x;
  const int w = t >> 6, lane = t & 63, l15 = lane & 15, kg = lane >> 4;
  const int row0 = blockIdx.x * 64, col0 = blockIdx.y * 64;
  const int sr = t >> 2;
  const int sc = (t & 3) * 16;
  const int sswz = (sr & 7) << 4;
  const int sbase = sr * 128 + sc * 2;
  f32x4 acc[4];
#pragma unroll
  for (int ct = 0; ct < 4; ct++) acc[ct] = (f32x4){0.f, 0.f, 0.f, 0.f};

  const int r = row0 + sr;
  const float v0 = vol[r], d0 = dist[r], e0 = ec[r];

  for (int kb = 0; kb < K; kb += 64) {
    __syncthreads();
    {
      const int kc = kb + sc;  // 16-run never straddles the 512 boundary
      float4 a0, a1, a2, a3;
      if (kc < 512) {
        const float* Ap = A + (size_t)r * 1024 + kc;
        a0 = *(const float4*)(Ap);
        a1 = *(const float4*)(Ap + 4);
        a2 = *(const float4*)(Ap + 8);
        a3 = *(const float4*)(Ap + 12);
      } else {
        const int j = kc - 512;
        float tmp[16];
#pragma unroll
        for (int i = 0; i < 16; i++) {
          float v = v0 * w1[j + i] + d0 * w1[512 + j + i] + e0 * w1[1024 + j + i] + b1[j + i];
          tmp[i] = fmaxf(v, 0.0f);
        }
        a0 = make_float4(tmp[0], tmp[1], tmp[2], tmp[3]);
        a1 = make_float4(tmp[4], tmp[5], tmp[6], tmp[7]);
        a2 = make_float4(tmp[8], tmp[9], tmp[10], tmp[11]);
        a3 = make_float4(tmp[12], tmp[13], tmp[14], tmp[15]);
      }
      union { bfx8 v; unsigned u[4]; } vh0, vh1, vl0, vl1;
      split2pk(a0.x, a0.y, vh0.u[0], vl0.u[0]);
      split2pk(a0.z, a0.w, vh0.u[1], vl0.u[1]);
      split2pk(a1.x, a1.y, vh0.u[2], vl0.u[2]);
      split2pk(a1.z, a1.w, vh0.u[3], vl0.u[3]);
      split2pk(a2.x, a2.y, vh1.u[0], vl1.u[0]);
      split2pk(a2.z, a2.w, vh1.u[1], vl1.u[1]);
      split2pk(a3.x, a3.y, vh1.u[2], vl1.u[2]);
      split2pk(a3.z, a3.w, vh1.u[3], vl1.u[3]);
      *(bfx8*)(pAh + ((sbase) ^ sswz)) = vh0.v;
      *(bfx8*)(pAh + ((sbase + 16) ^ sswz)) = vh1.v;
      *(bfx8*)(pAl + ((sbase) ^ sswz)) = vl0.v;
      *(bfx8*)(pAl + ((sbase + 16) ^ sswz)) = vl1.v;
    }
    {
      const ushort_t* Bph = Bh + (size_t)(col0 + sr) * K + kb + sc;
      const ushort_t* Bpl = Bl + (size_t)(col0 + sr) * K + kb + sc;
      bfx8 b0 = *(const bfx8*)Bph, b1v = *(const bfx8*)(Bph + 8);
      bfx8 c0v = *(const bfx8*)Bpl, c1v = *(const bfx8*)(Bpl + 8);
      *(bfx8*)(pBh + ((sbase) ^ sswz)) = b0;
      *(bfx8*)(pBh + ((sbase + 16) ^ sswz)) = b1v;
      *(bfx8*)(pBl + ((sbase) ^ sswz)) = c0v;
      *(bfx8*)(pBl + ((sbase + 16) ^ sswz)) = c1v;
    }
    __syncthreads();
#pragma unroll
    for (int ks = 0; ks < 2; ks++) {
      const int arow = w * 16 + l15;
      const int k2 = (ks * 32 + kg * 8) * 2;
      const int aoff = (arow * 128 + k2) ^ ((arow & 7) << 4);
      bfx8 ah = *(const bfx8*)(pAh + aoff);
      bfx8 al = *(const bfx8*)(pAl + aoff);
#pragma unroll
      for (int ct = 0; ct < 4; ct++) {
        const int bcol = ct * 16 + l15;
        const int boff = (bcol * 128 + k2) ^ ((bcol & 7) << 4);
        bfx8 bh = *(const bfx8*)(pBh + boff);
        bfx8 bl = *(const bfx8*)(pBl + boff);
        acc[ct] = MFMA16(ah, bh, acc[ct]);
        acc[ct] = MFMA16(al, bh, acc[ct]);
        acc[ct] = MFMA16(ah, bl, acc[ct]);
      }
    }
  }
#pragma unroll
  for (int ct = 0; ct < 4; ct++)
#pragma unroll
    for (int j = 0; j < 4; j++) {
      int rr = row0 + w * 16 + kg * 4 + j;
      int cc = col0 + ct * 16 + l15;
      float v = acc[ct][j] + bias[cc];
      C[(size_t)rr * N + cc] = fmaxf(v, 0.0f);
    }
}

// ---------- generic f32 GEMM (small classifier layer + fallback) ----------
template <int ACT>
__global__ __launch_bounds__(256) void k_gemm(const float* __restrict__ A,
                                              const float* __restrict__ W,
                                              const float* __restrict__ bias,
                                              float* __restrict__ C, int M, int N, int K,
                                              int ldc, int cof) {
  __shared__ float sA[64][17];
  __shared__ float sW[16][64];
  const int t = threadIdx.x;
  const int row0 = blockIdx.x * 64, col0 = blockIdx.y * 64;
  const int tr = t >> 4, tc = t & 15;
  const int la_r = t >> 2, la_c = (t & 3) * 4;
  const int lw_r = t >> 4, lw_c = (t & 15) * 4;
  float acc[4][4] = {};
  for (int kb = 0; kb < K; kb += 16) {
    __syncthreads();
    float4 av = *(const float4*)(A + (size_t)(row0 + la_r) * K + kb + la_c);
    sA[la_r][la_c + 0] = av.x; sA[la_r][la_c + 1] = av.y;
    sA[la_r][la_c + 2] = av.z; sA[la_r][la_c + 3] = av.w;
    float4 wv = *(const float4*)(W + (size_t)(kb + lw_r) * N + col0 + lw_c);
    *(float4*)&sW[lw_r][lw_c] = wv;
    __syncthreads();
#pragma unroll
    for (int kk = 0; kk < 16; kk++) {
      float a0 = sA[tr * 4 + 0][kk], a1 = sA[tr * 4 + 1][kk];
      float a2 = sA[tr * 4 + 2][kk], a3 = sA[tr * 4 + 3][kk];
      float4 w4 = *(const float4*)&sW[kk][tc * 4];
      acc[0][0] = fmaf(a0, w4.x, acc[0][0]); acc[0][1] = fmaf(a0, w4.y, acc[0][1]);
      acc[0][2] = fmaf(a0, w4.z, acc[0][2]); acc[0][3] = fmaf(a0, w4.w, acc[0][3]);
      acc[1][0] = fmaf(a1, w4.x, acc[1][0]); acc[1][1] = fmaf(a1, w4.y, acc[1][1]);
      acc[1][2] = fmaf(a1, w4.z, acc[1][2]); acc[1][3] = fmaf(a1, w4.w, acc[1][3]);
      acc[2][0] = fmaf(a2, w4.x, acc[2][0]); acc[2][1] = fmaf(a2, w4.y, acc[2][1]);
      acc[2][2] = fmaf(a2, w4.z, acc[2][2]); acc[2][3] = fmaf(a2, w4.w, acc[2][3]);
      acc[3][0] = fmaf(a3, w4.x, acc[3][0]); acc[3][1] = fmaf(a3, w4.y, acc[3][1]);
      acc[3][2] = fmaf(a3, w4.z, acc[3][2]); acc[3][3] = fmaf(a3, w4.w, acc[3][3]);
    }
  }
#pragma unroll
  for (int i = 0; i < 4; i++) {
    int r = row0 + tr * 4 + i;
#pragma unroll
    for (int j = 0; j < 4; j++) {
      int c = col0 + tc * 4 + j;
      float v = acc[i][j] + bias[c];
      if (ACT == 1) v = fmaxf(v, 0.0f);
      C[(size_t)r * ldc + cof + c] = v;
    }
  }
}

// ---------- fused GATv2 per node: scores + online softmax + aggregate ----------
// xlr packed [2048][1024]: cols 0-511 = xl, 512-1023 = xr.
template <int ACT>
__global__ __launch_bounds__(256) void k_gat(
    const float* __restrict__ xlr, const float* __restrict__ att,
    const int* __restrict__ row_ptr, const int* __restrict__ edge_list,
    const int* __restrict__ ei, const float* __restrict__ bias,
    float* __restrict__ out) {
  __shared__ float sXr[512];
  __shared__ float sPb[32][8];
  __shared__ int sSrc[32];
  __shared__ float sM[8], sD[8], sScale[8];
  const int n = blockIdx.x, t = threadIdx.x;
  const int wv = t >> 6, l = t & 63;
  float attr[8];
#pragma unroll
  for (int h = 0; h < 8; h++) attr[h] = att[h * 64 + l];
  for (int i = t; i < 512; i += 256) sXr[i] = xlr[(size_t)n * 1024 + 512 + i];
  if (t < 8) { sM[t] = -1e30f; sD[t] = 0.f; }
  const int f0 = t, f1 = t + 256;
  const int h0 = f0 >> 6, h1 = f1 >> 6;
  float acc0 = 0.f, acc1 = 0.f;
  const int beg = row_ptr[n], end = row_ptr[n + 1];
  __syncthreads();
  for (int b = beg; b < end; b += 32) {
    const int cnt = min(32, end - b);
    // phase A: per-edge scores (one wave per edge)
    for (int i = wv; i < cnt; i += 4) {
      const int e = edge_list[b + i];
      const int s = e_src(ei, e);
      const float* xs = xlr + (size_t)s * 1024;
      float ps[8];
#pragma unroll
      for (int h = 0; h < 8; h++) {
        float v = xs[h * 64 + l] + sXr[h * 64 + l];
        v = v > 0.f ? v : 0.2f * v;  // leaky_relu(0.2)
        ps[h] = v * attr[h];
      }
#pragma unroll
      for (int off = 1; off < 64; off <<= 1)
#pragma unroll
        for (int h = 0; h < 8; h++) ps[h] += __shfl_xor(ps[h], off);
      if (l == 0) {
        sSrc[i] = s;
#pragma unroll
        for (int h = 0; h < 8; h++) sPb[i][h] = ps[h];
      }
    }
    __syncthreads();
    // phase B: online softmax bookkeeping (8 threads, one per head)
    if (t < 8) {
      float m = sM[t];
      for (int i = 0; i < cnt; i++) m = fmaxf(m, sPb[i][t]);
      float scale = expf(sM[t] - m);
      float d = sD[t] * scale;
      for (int i = 0; i < cnt; i++) {
        float p = expf(sPb[i][t] - m);
        sPb[i][t] = p;
        d += p;
      }
      sM[t] = m; sD[t] = d; sScale[t] = scale;
    }
    __syncthreads();
    // phase C: rescale + accumulate
    acc0 *= sScale[h0];
    acc1 *= sScale[h1];
    for (int i = 0; i < cnt; i++) {
      const float* xs = xlr + (size_t)sSrc[i] * 1024;
      acc0 = fmaf(sPb[i][h0], xs[f0], acc0);
      acc1 = fmaf(sPb[i][h1], xs[f1], acc1);
    }
    __syncthreads();  // protect sPb/sM/sSrc before next batch
  }
  float v0 = acc0 / sD[h0] + bias[f0];
  float v1 = acc1 / sD[h1] + bias[f1];
  if (ACT == 1) { v0 = fmaxf(v0, 0.f); v1 = fmaxf(v1, 0.f); }
  out[(size_t)n * 512 + f0] = v0;
  out[(size_t)n * 512 + f1] = v1;
}

// ---------- logits + BCE loss + per-graph argmax hits ----------
__global__ __launch_bounds__(1024) void k_final(const float* __restrict__ hc2,
                                                const float* __restrict__ w3,
                                                const float* __restrict__ b3,
                                                const float* __restrict__ y,
                                                float* __restrict__ out) {
  __shared__ float sL[2048];
  __shared__ float sRed[1024];
  __shared__ float sW[64];
  const int t = threadIdx.x;
  if (t < 64) sW[t] = w3[t];
  __syncthreads();
  float lp = 0.0f;
  for (int n = t; n < 2048; n += 1024) {
    const float4* r = (const float4*)(hc2 + (size_t)n * 64);
    float a = 0.0f;
#pragma unroll
    for (int k = 0; k < 16; k++) {
      float4 v = r[k];
      a += v.x * sW[4 * k] + v.y * sW[4 * k + 1] + v.z * sW[4 * k + 2] + v.w * sW[4 * k + 3];
    }
    a += b3[0];
    sL[n] = a;
    lp += fmaxf(a, 0.0f) - a * y[n] + log1pf(expf(-fabsf(a)));
  }
  sRed[t] = lp;
  __syncthreads();
  for (int off = 512; off > 0; off >>= 1) {
    if (t < off) sRed[t] += sRed[t + off];
    __syncthreads();
  }
  if (t == 0) out[0] = sRed[0] * (1.0f / 2048.0f);
  __syncthreads();
  float hit = 0.0f;
  if (t < 64) {
    const int base = t * NPG;
    float bl = sL[base]; int bi = 0;
    float by = y[base];  int byi = 0;
    for (int i = 1; i < NPG - 1; i++) {  // [:, :-1] -> 31 entries, first-max tie rule
      float v = sL[base + i];
      if (v > bl) { bl = v; bi = i; }
      float w = y[base + i];
      if (w > by) { by = w; byi = i; }
    }
    hit = (bi == byi) ? 1.0f : 0.0f;
  }
  __syncthreads();
  sRed[t] = hit;
  __syncthreads();
  for (int off = 512; off > 0; off >>= 1) {
    if (t < off) sRed[t] += sRed[t + off];
    __syncthreads();
  }
  if (t == 0) out[1] = sRed[0] * (1.0f / 64.0f);
}

// ---------- workspace layout (float units) ----------
constexpr size_t OFF_XCAT = 0;                                  // [2048,1024] (also xl|xr)
constexpr size_t OFF_X1   = OFF_XCAT + (size_t)2048 * 1024;     // [2048,512]
constexpr size_t OFF_XL   = OFF_X1 + (size_t)2048 * 512;        // (fallback only)
constexpr size_t OFF_XR   = OFF_XL + (size_t)2048 * 512;
constexpr size_t OFF_G1   = OFF_XR + (size_t)2048 * 512;
constexpr size_t OFF_G2   = OFF_G1 + (size_t)2048 * 512;
constexpr size_t OFF_HC1  = OFF_G2 + (size_t)2048 * 512;        // [2048,64]
constexpr size_t OFF_HC2  = OFF_HC1 + (size_t)2048 * 64;
constexpr size_t OFF_SC   = OFF_HC2 + (size_t)2048 * 64;        // (legacy, unused)
constexpr size_t OFF_P    = OFF_SC + (size_t)N_EDGE_TOT * 8;
constexpr size_t OFF_M    = OFF_P + (size_t)N_EDGE_TOT * 8;
constexpr size_t OFF_DEN  = OFF_M + (size_t)2048 * 8;
constexpr size_t OFF_RP   = OFF_DEN + (size_t)2048 * 8;         // int [2052]
constexpr size_t OFF_CNT  = OFF_RP + 2052;                      // int [2048]
constexpr size_t OFF_EL   = OFF_CNT + 2048;                     // int [34816]
constexpr size_t OFF_USH  = OFF_EL + 34816;                     // ushort regions (16B aligned)

constexpr size_t WS_NEED_FULL = (OFF_USH + (U_END + 1) / 2) * sizeof(float);

extern "C" void kernel_launch(void* const* d_in, const int* in_sizes, int n_in,
                              void* d_out, int out_size, void* d_ws, size_t ws_size,
                              hipStream_t stream) {
  const float* pcd   = (const float*)d_in[0];
  const float* vol   = (const float*)d_in[1];
  const float* dist  = (const float*)d_in[2];
  const float* ecnt  = (const float*)d_in[3];
  const float* y     = (const float*)d_in[4];
  const float* pn_w1 = (const float*)d_in[5];
  const float* pn_w2 = (const float*)d_in[6];
  const float* pn_w3 = (const float*)d_in[7];
  const float* pn_w4 = (const float*)d_in[8];
  const float* pn_w5 = (const float*)d_in[9];
  const float* mf_w1 = (const float*)d_in[10];
  const float* mf_b1 = (const float*)d_in[11];
  const float* mf_w2 = (const float*)d_in[12];
  const float* mf_b2 = (const float*)d_in[13];
  const float* g1_wl = (const float*)d_in[14];
  const float* g1_bl = (const float*)d_in[15];
  const float* g1_wr = (const float*)d_in[16];
  const float* g1_br = (const float*)d_in[17];
  const float* g1_at = (const float*)d_in[18];
  const float* g1_bi = (const float*)d_in[19];
  const float* g2_wl = (const float*)d_in[20];
  const float* g2_bl = (const float*)d_in[21];
  const float* g2_wr = (const float*)d_in[22];
  const float* g2_br = (const float*)d_in[23];
  const float* g2_at = (const float*)d_in[24];
  const float* g2_bi = (const float*)d_in[25];
  const float* cl_w1 = (const float*)d_in[26];
  const float* cl_b1 = (const float*)d_in[27];
  const float* cl_w2 = (const float*)d_in[28];
  const float* cl_b2 = (const float*)d_in[29];
  const float* cl_w3 = (const float*)d_in[30];
  const float* cl_b3 = (const float*)d_in[31];
  const int*   ei    = (const int*)d_in[32];
  float* out = (float*)d_out;
  float* ws  = (float*)d_ws;

  float* xcat = ws + OFF_XCAT;   // pointnet output; later reused as xl|xr
  float* x1   = ws + OFF_X1;
  float* g1o  = ws + OFF_G1;
  float* g2o  = ws + OFF_G2;
  float* hc1  = ws + OFF_HC1;
  float* hc2  = ws + OFF_HC2;
  int* rp     = (int*)(ws + OFF_RP);
  int* cnt    = (int*)(ws + OFF_CNT);
  int* el     = (int*)(ws + OFF_EL);
  ushort_t* ush = (ushort_t*)(ws + OFF_USH);

  const bool full = (ws_size >= WS_NEED_FULL);

  // --- build CSR by dst (shared by both GAT layers) ---
  hipMemsetAsync(cnt, 0, 2048 * sizeof(int), stream);
  k_hist<<<(N_EDGE_TOT + 255) / 256, 256, 0, stream>>>(ei, cnt);
  k_scan<<<1, 256, 0, stream>>>(cnt, rp);  // also re-zeros cnt for k_scatter
  k_scatter<<<(N_EDGE_TOT + 255) / 256, 256, 0, stream>>>(ei, rp, cnt, el);

  // --- weight prep: ALL splits in one launch ---
  k_split_all<<<412, 256, 0, stream>>>(pn_w2, pn_w3, pn_w4, pn_w5, mf_w2,
                                       g1_wl, g1_wr, g2_wl, g2_wr, cl_w1,
                                       ush, full ? 1 : 0);

  // --- PointNet + multi-feature (vdf fused into mf GEMM) ---
  k_pointnet<<<N_NODES, 512, 0, stream>>>(pcd, pn_w1,
      ush + U_W2H, ush + U_W2L, ush + U_W3H, ush + U_W3L,
      ush + U_W4H, ush + U_W4L, ush + U_W5H, ush + U_W5L, xcat);
  if (full) {
    k_mgemm_mf<<<dim3(32, 8), 256, 0, stream>>>(xcat, vol, dist, ecnt, mf_w1, mf_b1,
                                                ush + U_MFH, ush + U_MFL, mf_b2, x1);
  } else {
    k_vdf<<<2048 * 512 / 256, 256, 0, stream>>>(vol, dist, ecnt, mf_w1, mf_b1, xcat);
    k_gemm<1><<<dim3(32, 8), 256, 0, stream>>>(xcat, mf_w2, mf_b2, x1, 2048, 512, 1024, 512, 0);
  }

  // --- GAT layers (merged wl|wr transform -> xcat reused as [2048][1024]) ---
  if (full) {
    k_mgemm<0><<<dim3(32, 16), 256, 0, stream>>>(x1, ush + U_G1H, ush + U_G1L, g1_bl, g1_br, xcat, 2048, 1024, 512);
    k_gat<1><<<N_NODES, 256, 0, stream>>>(xcat, g1_at, rp, el, ei, g1_bi, g1o);
    k_mgemm<0><<<dim3(32, 16), 256, 0, stream>>>(g1o, ush + U_G2H, ush + U_G2L, g2_bl, g2_br, xcat, 2048, 1024, 512);
    k_gat<0><<<N_NODES, 256, 0, stream>>>(xcat, g2_at, rp, el, ei, g2_bi, g2o);
    k_mgemm<1><<<dim3(32, 1), 256, 0, stream>>>(g2o, ush + U_CL1H, ush + U_CL1L, cl_b1, cl_b1, hc1, 2048, 64, 512);
  } else {
    k_gemm<0><<<dim3(32, 8), 256, 0, stream>>>(x1, g1_wl, g1_bl, xcat, 2048, 512, 512, 1024, 0);
    k_gemm<0><<<dim3(32, 8), 256, 0, stream>>>(x1, g1_wr, g1_br, xcat, 2048, 512, 512, 1024, 512);
    k_gat<1><<<N_NODES, 256, 0, stream>>>(xcat, g1_at, rp, el, ei, g1_bi, g1o);
    k_gemm<0><<<dim3(32, 8), 256, 0, stream>>>(g1o, g2_wl, g2_bl, xcat, 2048, 512, 512, 1024, 0);
    k_gemm<0><<<dim3(32, 8), 256, 0, stream>>>(g1o, g2_wr, g2_br, xcat, 2048, 512, 512, 1024, 512);
    k_gat<0><<<N_NODES, 256, 0, stream>>>(xcat, g2_at, rp, el, ei, g2_bi, g2o);
    k_gemm<1><<<dim3(32, 1), 256, 0, stream>>>(g2o, cl_w1, cl_b1, hc1, 2048, 64, 512, 64, 0);
  }
  k_gemm<1><<<dim3(32, 1), 256, 0, stream>>>(hc1, cl_w2, cl_b2, hc2, 2048, 64, 64, 64, 0);
  k_final<<<1, 1024, 0, stream>>>(hc2, cl_w3, cl_b3, y, out);
}